// Round 1
// baseline (958.095 us; speedup 1.0000x reference)
//
#include <hip/hip_runtime.h>
#include <hip/hip_bf16.h>
#include <cmath>
#include <cstdint>

typedef unsigned int u32;
typedef unsigned char u8;

#define Gn 2048
#define Hd 256

// ---------------------------------------------------------------------------
// Mask dtype detection: bool masks may arrive as int8 (numpy bool_), int32,
// or float32. Scan first 256KB of adj_pp: int32(1) has nonzero bytes only at
// offset%4==0; int8 has them everywhere; f32(1.0f) has none at offset%4==0.
// flag: 0=int32, 1=int8, 2=float32
// ---------------------------------------------------------------------------
__global__ void detect_fmt_kernel(const u8* __restrict__ src, int* __restrict__ flag) {
    __shared__ int c0s, c123s;
    if (threadIdx.x == 0) { c0s = 0; c123s = 0; }
    __syncthreads();
    int c0 = 0, c123 = 0;
    for (int i = threadIdx.x; i < (1 << 18); i += 256) {
        if (src[i]) { if (i & 3) c123++; else c0++; }
    }
    if (c0) atomicAdd(&c0s, c0);
    if (c123) atomicAdd(&c123s, c123);
    __syncthreads();
    if (threadIdx.x == 0) {
        int f;
        if (c0s > 0 && c123s == 0) f = 0;
        else if (c0s > 0) f = 1;
        else f = 2;
        *flag = f;
    }
}

// pack mask[rows][cols] (True=attend) into bitmask words [rows][cols/32]
__global__ void pack_mask_kernel(const u8* __restrict__ src, const int* __restrict__ flag,
                                 u32* __restrict__ bits, int nwords_per_row, int ncols) {
    int idx = blockIdx.x * 256 + threadIdx.x;
    int row = idx / nwords_per_row;
    int w = idx - row * nwords_per_row;
    int f = *flag;
    u32 v = 0;
    if (f == 1) {
        const u8* p = src + (long)row * ncols + w * 32;
        #pragma unroll
        for (int j = 0; j < 32; ++j) v |= (p[j] ? 1u : 0u) << j;
    } else if (f == 0) {
        const int* p = (const int*)src + (long)row * ncols + w * 32;
        #pragma unroll
        for (int j = 0; j < 32; ++j) v |= (p[j] ? 1u : 0u) << j;
    } else {
        const float* p = (const float*)src + (long)row * ncols + w * 32;
        #pragma unroll
        for (int j = 0; j < 32; ++j) v |= (p[j] != 0.f ? 1u : 0u) << j;
    }
    bits[idx] = v;
}

// ---------------------------------------------------------------------------
// fp32 tiled GEMM: C[M,N] (+)= A[M,K] @ B[K,N] (+bias) (+relu)
// 64x64 tile, BK=16, 256 threads, 4x4 microtile/thread.
// blockIdx.z strides B and C (used for fused QKV: 3 weight mats).
// ---------------------------------------------------------------------------
template <int BETA, int RELU>
__global__ __launch_bounds__(256) void gemm_kernel(
    const float* __restrict__ A, const float* __restrict__ B,
    const float* __restrict__ bias, float* __restrict__ C,
    int M, int N, int K, long sB, long sC)
{
    B += (long)blockIdx.z * sB;
    C += (long)blockIdx.z * sC;
    __shared__ float As[16][68];
    __shared__ float Bs[16][68];
    const int tid = threadIdx.x;
    const int tx = tid & 15, ty = tid >> 4;
    const int row0 = blockIdx.x * 64, col0 = blockIdx.y * 64;
    float acc[4][4] = {};
    for (int k0 = 0; k0 < K; k0 += 16) {
        {
            const int r = tid >> 2, c4 = (tid & 3) << 2;
            float4 a = *(const float4*)&A[(long)(row0 + r) * K + k0 + c4];
            As[c4 + 0][r] = a.x; As[c4 + 1][r] = a.y;
            As[c4 + 2][r] = a.z; As[c4 + 3][r] = a.w;
            const int rb = tid >> 4, cb = (tid & 15) << 2;
            *(float4*)&Bs[rb][cb] = *(const float4*)&B[(long)(k0 + rb) * N + col0 + cb];
        }
        __syncthreads();
        #pragma unroll
        for (int k = 0; k < 16; ++k) {
            float4 a4 = *(const float4*)&As[k][ty << 2];
            float4 b4 = *(const float4*)&Bs[k][tx << 2];
            float av[4] = {a4.x, a4.y, a4.z, a4.w};
            float bv[4] = {b4.x, b4.y, b4.z, b4.w};
            #pragma unroll
            for (int i = 0; i < 4; ++i)
                #pragma unroll
                for (int j = 0; j < 4; ++j)
                    acc[i][j] += av[i] * bv[j];
        }
        __syncthreads();
    }
    #pragma unroll
    for (int i = 0; i < 4; ++i) {
        const long r = row0 + (ty << 2) + i;
        float bx[4];
        #pragma unroll
        for (int j = 0; j < 4; ++j)
            bx[j] = acc[i][j] + (bias ? bias[col0 + (tx << 2) + j] : 0.f);
        if (BETA) {
            float4 old = *(const float4*)&C[r * N + col0 + (tx << 2)];
            bx[0] += old.x; bx[1] += old.y; bx[2] += old.z; bx[3] += old.w;
        }
        if (RELU) {
            #pragma unroll
            for (int j = 0; j < 4; ++j) bx[j] = fmaxf(bx[j], 0.f);
        }
        float4 c4v; c4v.x = bx[0]; c4v.y = bx[1]; c4v.z = bx[2]; c4v.w = bx[3];
        *(float4*)&C[r * N + col0 + (tx << 2)] = c4v;
    }
}

// ---------------------------------------------------------------------------
// LayerNorm over rows of 256 (+optional relu). One wave per row.
// ---------------------------------------------------------------------------
template <int RELU>
__global__ __launch_bounds__(64) void ln_kernel(
    const float* __restrict__ X, const float* __restrict__ gw,
    const float* __restrict__ bw, float* __restrict__ Y)
{
    const int row = blockIdx.x, tid = threadIdx.x;
    const float4 x = *(const float4*)&X[(long)row * 256 + (tid << 2)];
    float s = x.x + x.y + x.z + x.w;
    float s2 = x.x * x.x + x.y * x.y + x.z * x.z + x.w * x.w;
    #pragma unroll
    for (int o = 1; o < 64; o <<= 1) { s += __shfl_xor(s, o); s2 += __shfl_xor(s2, o); }
    const float mean = s * (1.f / 256.f);
    const float var = s2 * (1.f / 256.f) - mean * mean;
    const float rs = rsqrtf(var + 1e-5f);
    const float4 g4 = *(const float4*)&gw[tid << 2];
    const float4 b4 = *(const float4*)&bw[tid << 2];
    float4 y;
    y.x = (x.x - mean) * rs * g4.x + b4.x;
    y.y = (x.y - mean) * rs * g4.y + b4.y;
    y.z = (x.z - mean) * rs * g4.z + b4.z;
    y.w = (x.w - mean) * rs * g4.w + b4.w;
    if (RELU) {
        y.x = fmaxf(y.x, 0.f); y.y = fmaxf(y.y, 0.f);
        y.z = fmaxf(y.z, 0.f); y.w = fmaxf(y.w, 0.f);
    }
    *(float4*)&Y[(long)row * 256 + (tid << 2)] = y;
}

// ---------------------------------------------------------------------------
// Flash-style masked MHA. qkv=[3][2048][256]; block=(head, 32-query tile).
// 256 threads: 32 q-rows x 8 threads; each thread owns 8 keys (scores) and
// 4 output dims. Online softmax; -1e9 masking matches the reference exactly
// (including all-masked rows -> uniform).  K/V LDS tiles are XOR-swizzled by
// (row>>3) so the hot ds_read_b128 loops are bank-conflict-free.
// ---------------------------------------------------------------------------
__global__ __launch_bounds__(256) void attn_kernel(
    const float* __restrict__ qkv, const u32* __restrict__ maskbits,
    float* __restrict__ ctx)
{
    const int h = blockIdx.x, qt = blockIdx.y;
    const float scale = 0.17677669529663687f; // 1/sqrt(32)
    const float* Qp = qkv;
    const float* Kp = qkv + (long)Gn * Hd;
    const float* Vp = qkv + 2L * Gn * Hd;
    __shared__ float Qs[32][32];
    __shared__ float Ks[64 * 32];
    __shared__ float Vs[64 * 32];
    __shared__ float Ps[32][65];
    const int tid = threadIdx.x;
    const int qlocal = tid >> 3, sub = tid & 7;
    const int qglob = qt * 32 + qlocal;
    {
        const int r = tid >> 3, c4 = (tid & 7) << 2;
        *(float4*)&Qs[r][c4] =
            *(const float4*)&Qp[(long)(qt * 32 + r) * Hd + h * 32 + c4];
    }
    __syncthreads();
    float qreg[32];
    #pragma unroll
    for (int g = 0; g < 8; ++g) {
        float4 qv = *(const float4*)&Qs[qlocal][g << 2];
        qreg[4 * g + 0] = qv.x; qreg[4 * g + 1] = qv.y;
        qreg[4 * g + 2] = qv.z; qreg[4 * g + 3] = qv.w;
    }
    float m = -INFINITY, l = 0.f;
    float acc0 = 0.f, acc1 = 0.f, acc2 = 0.f, acc3 = 0.f;
    for (int kt = 0; kt < Gn / 64; ++kt) {
        __syncthreads(); // previous AV reads of Ks/Vs/Ps complete
        #pragma unroll
        for (int it = 0; it < 2; ++it) {
            const int r = (tid >> 3) + it * 32;
            const int cg = tid & 7;
            const int pg = cg ^ (r >> 3);
            *(float4*)&Ks[r * 32 + (pg << 2)] =
                *(const float4*)&Kp[(long)(kt * 64 + r) * Hd + h * 32 + (cg << 2)];
            *(float4*)&Vs[r * 32 + (pg << 2)] =
                *(const float4*)&Vp[(long)(kt * 64 + r) * Hd + h * 32 + (cg << 2)];
        }
        __syncthreads();
        u32 mbits = 0xffu;
        if (maskbits) {
            u32 w = maskbits[(long)qglob * 64 + kt * 2 + (sub >> 2)];
            mbits = w >> ((sub & 3) << 3);
        }
        float sc[8];
        #pragma unroll
        for (int i = 0; i < 8; ++i) {
            const int kk = sub * 8 + i;
            const float* kr = &Ks[kk * 32];
            float s = 0.f;
            #pragma unroll
            for (int g = 0; g < 8; ++g) {
                float4 kv = *(const float4*)&kr[(g ^ sub) << 2];
                s += kv.x * qreg[4 * g + 0] + kv.y * qreg[4 * g + 1] +
                     kv.z * qreg[4 * g + 2] + kv.w * qreg[4 * g + 3];
            }
            s *= scale;
            if (!((mbits >> i) & 1u)) s = -1e9f;
            sc[i] = s;
        }
        float mt = sc[0];
        #pragma unroll
        for (int i = 1; i < 8; ++i) mt = fmaxf(mt, sc[i]);
        mt = fmaxf(mt, __shfl_xor(mt, 1));
        mt = fmaxf(mt, __shfl_xor(mt, 2));
        mt = fmaxf(mt, __shfl_xor(mt, 4));
        const float mnew = fmaxf(m, mt);
        const float fac = __expf(m - mnew); // m=-inf first tile -> 0
        float ps = 0.f;
        #pragma unroll
        for (int i = 0; i < 8; ++i) {
            const float p = __expf(sc[i] - mnew);
            ps += p;
            Ps[qlocal][sub * 8 + i] = p;
        }
        ps += __shfl_xor(ps, 1); ps += __shfl_xor(ps, 2); ps += __shfl_xor(ps, 4);
        l = l * fac + ps;
        m = mnew;
        acc0 *= fac; acc1 *= fac; acc2 *= fac; acc3 *= fac;
        __syncthreads(); // Ps visible to whole row group
        #pragma unroll 4
        for (int k = 0; k < 64; ++k) {
            const float p = Ps[qlocal][k];
            float4 vv = *(const float4*)&Vs[k * 32 + ((sub ^ (k >> 3)) << 2)];
            acc0 += p * vv.x; acc1 += p * vv.y; acc2 += p * vv.z; acc3 += p * vv.w;
        }
    }
    const float inv = 1.f / l;
    float4 o; o.x = acc0 * inv; o.y = acc1 * inv; o.z = acc2 * inv; o.w = acc3 * inv;
    *(float4*)&ctx[(long)qglob * Hd + h * 32 + (sub << 2)] = o;
}

// ---------------------------------------------------------------------------
// Aggregation tail
// ---------------------------------------------------------------------------
__global__ __launch_bounds__(256) void gate2_kernel(
    const float* __restrict__ g1, const float* __restrict__ w2,
    const float* __restrict__ b2, float* __restrict__ gv)
{
    int g = blockIdx.x * 256 + threadIdx.x;
    float s = 0.f;
    #pragma unroll
    for (int k = 0; k < 128; k += 4) {
        float4 x = *(const float4*)&g1[(long)g * 128 + k];
        float4 w = *(const float4*)&w2[k];
        s += x.x * w.x + x.y * w.y + x.z * w.z + x.w * w.w;
    }
    gv[g] = s + b2[0];
}

__global__ __launch_bounds__(256) void softmax2048_kernel(float* __restrict__ gv) {
    __shared__ float red[4];
    const int tid = threadIdx.x;
    float v[8];
    float m = -INFINITY;
    #pragma unroll
    for (int i = 0; i < 8; ++i) { v[i] = gv[tid + (i << 8)]; m = fmaxf(m, v[i]); }
    #pragma unroll
    for (int o = 1; o < 64; o <<= 1) m = fmaxf(m, __shfl_xor(m, o));
    if ((tid & 63) == 0) red[tid >> 6] = m;
    __syncthreads();
    m = fmaxf(fmaxf(red[0], red[1]), fmaxf(red[2], red[3]));
    __syncthreads();
    float s = 0.f;
    #pragma unroll
    for (int i = 0; i < 8; ++i) { v[i] = __expf(v[i] - m); s += v[i]; }
    #pragma unroll
    for (int o = 1; o < 64; o <<= 1) s += __shfl_xor(s, o);
    if ((tid & 63) == 0) red[tid >> 6] = s;
    __syncthreads();
    s = red[0] + red[1] + red[2] + red[3];
    const float inv = 1.f / s;
    #pragma unroll
    for (int i = 0; i < 8; ++i) gv[tid + (i << 8)] = v[i] * inv;
}

// pooled[col] = sum_r a[r]*t[r][col]; grid 8 blocks x 32 cols
__global__ __launch_bounds__(256) void wsum_kernel(
    const float* __restrict__ a, const float* __restrict__ t, float* __restrict__ pooled)
{
    __shared__ float red[8][32];
    const int tid = threadIdx.x;
    const int col = blockIdx.x * 32 + (tid & 31);
    const int rg = tid >> 5;
    float s = 0.f;
    for (int r = rg; r < Gn; r += 8) s += a[r] * t[(long)r * 256 + col];
    red[rg][tid & 31] = s;
    __syncthreads();
    if (rg == 0) {
        float tot = 0.f;
        #pragma unroll
        for (int i = 0; i < 8; ++i) tot += red[i][tid & 31];
        pooled[col] = tot;
    }
}

__global__ __launch_bounds__(256) void head_kernel(
    const float* __restrict__ pooled, const float* __restrict__ hw,
    const float* __restrict__ hb, float* __restrict__ out)
{
    __shared__ float red0[4], red1[4];
    const int tid = threadIdx.x;
    const float p = pooled[tid];
    float s0 = p * hw[tid * 2 + 0];
    float s1 = p * hw[tid * 2 + 1];
    #pragma unroll
    for (int o = 1; o < 64; o <<= 1) { s0 += __shfl_xor(s0, o); s1 += __shfl_xor(s1, o); }
    if ((tid & 63) == 0) { red0[tid >> 6] = s0; red1[tid >> 6] = s1; }
    __syncthreads();
    if (tid == 0) {
        out[0] = red0[0] + red0[1] + red0[2] + red0[3] + hb[0];
        out[1] = red1[0] + red1[1] + red1[2] + red1[3] + hb[1];
    }
}

// ---------------------------------------------------------------------------
extern "C" void kernel_launch(void* const* d_in, const int* in_sizes, int n_in,
                              void* d_out, int out_size, void* d_ws, size_t ws_size,
                              hipStream_t stream)
{
    (void)in_sizes; (void)n_in; (void)out_size; (void)ws_size;
    const float* gene_emb = (const float*)d_in[0];
    const float* pre_w1   = (const float*)d_in[3];
    const float* pre_b1   = (const float*)d_in[4];
    const float* pre_w2   = (const float*)d_in[5];
    const float* pre_b2   = (const float*)d_in[6];
    const float* pre_ln_g = (const float*)d_in[7];
    const float* pre_ln_b = (const float*)d_in[8];
    const float* wm       = (const float*)d_in[9];   // [4,4,256,256]
    const float* wsw      = (const float*)d_in[10];  // [3,4,256,256]
    const float* ln_g     = (const float*)d_in[11];  // [3,256] -> row 0
    const float* ln_b     = (const float*)d_in[12];
    const float* gate_w1  = (const float*)d_in[13];
    const float* gate_b1  = (const float*)d_in[14];
    const float* gate_w2  = (const float*)d_in[15];
    const float* gate_b2  = (const float*)d_in[16];
    const float* tr_w     = (const float*)d_in[17];
    const float* tr_b     = (const float*)d_in[18];
    const float* head_w   = (const float*)d_in[19];
    const float* head_b   = (const float*)d_in[20];
    const u8* adj_pp      = (const u8*)d_in[21];
    const u8* adj_rr      = (const u8*)d_in[22];
    // d_in[1],[2],[23],[24] (reaction/metab embeddings, inc_gpr, adj_mm): dead.

    const long NHf = (long)Gn * Hd; // 524288 floats
    float* wsf   = (float*)d_ws;
    float* tmp0  = wsf;
    float* xg    = tmp0 + NHf;
    float* xg1   = xg + NHf;
    float* qkv   = xg1 + NHf;
    float* ctxb  = qkv + 3 * NHf;
    float* g1    = ctxb + NHf;
    float* gatev = g1 + (long)Gn * 128;
    float* pooled = gatev + Gn;
    int* flag    = (int*)(pooled + 256);
    u32* bits_pp = (u32*)(flag + 64);
    u32* bits_rr = bits_pp + (long)Gn * 64;
    // total ws use ~16.8 MB

    const long W1 = 65536;      // one [256,256] matrix
    const long W44 = 4 * W1;    // one edge-type block in wm

    dim3 B256(256), B64g(2048), T64(64);

    // mask prep
    detect_fmt_kernel<<<dim3(1), B256, 0, stream>>>(adj_pp, flag);
    pack_mask_kernel<<<dim3(512), B256, 0, stream>>>(adj_pp, flag, bits_pp, 64, 2048);
    pack_mask_kernel<<<dim3(512), B256, 0, stream>>>(adj_rr, flag, bits_rr, 64, 2048);

    // preprocessor: xg = relu(LN(relu(LN(gene@w1+b1))@w2+b2))
    gemm_kernel<0, 0><<<dim3(32, 4, 1), B256, 0, stream>>>(gene_emb, pre_w1, pre_b1, tmp0, Gn, 256, 256, 0, 0);
    ln_kernel<1><<<B64g, T64, 0, stream>>>(tmp0, pre_ln_g, pre_ln_b, xg);
    gemm_kernel<0, 0><<<dim3(32, 4, 1), B256, 0, stream>>>(xg, pre_w2, pre_b2, tmp0, Gn, 256, 256, 0, 0);
    ln_kernel<1><<<B64g, T64, 0, stream>>>(tmp0, pre_ln_g, pre_ln_b, xg);

    // xg1 = xg (residual accumulator)
    hipMemcpyAsync(xg1, xg, NHf * sizeof(float), hipMemcpyDeviceToDevice, stream);

    // M block, edge type 0 (adj_pp): qkv from xg, xg1 += ctx@Wo
    gemm_kernel<0, 0><<<dim3(32, 4, 3), B256, 0, stream>>>(xg, wm + 0 * W44, nullptr, qkv, Gn, 256, 256, W1, NHf);
    attn_kernel<<<dim3(8, 64), B256, 0, stream>>>(qkv, bits_pp, ctxb);
    gemm_kernel<1, 0><<<dim3(32, 4, 1), B256, 0, stream>>>(ctxb, wm + 0 * W44 + 3 * W1, nullptr, xg1, Gn, 256, 256, 0, 0);

    // M block, edge type 1 (adj_rr): qkv from ORIGINAL xg
    gemm_kernel<0, 0><<<dim3(32, 4, 3), B256, 0, stream>>>(xg, wm + 1 * W44, nullptr, qkv, Gn, 256, 256, W1, NHf);
    attn_kernel<<<dim3(8, 64), B256, 0, stream>>>(qkv, bits_rr, ctxb);
    gemm_kernel<1, 0><<<dim3(32, 4, 1), B256, 0, stream>>>(ctxb, wm + 1 * W44 + 3 * W1, nullptr, xg1, Gn, 256, 256, 0, 0);

    // S block (full self-attn on xg1)
    gemm_kernel<0, 0><<<dim3(32, 4, 3), B256, 0, stream>>>(xg1, wsw, nullptr, qkv, Gn, 256, 256, W1, NHf);
    attn_kernel<<<dim3(8, 64), B256, 0, stream>>>(qkv, nullptr, ctxb);
    gemm_kernel<1, 0><<<dim3(32, 4, 1), B256, 0, stream>>>(ctxb, wsw + 3 * W1, nullptr, xg1, Gn, 256, 256, 0, 0);

    // final LN (gene branch) -> xg
    ln_kernel<0><<<B64g, T64, 0, stream>>>(xg1, ln_g, ln_b, xg);

    // aggregation: gate = relu(xg@gw1+gb1)@gw2+gb2; a=softmax; t=relu(xg@tr+b)
    gemm_kernel<0, 1><<<dim3(32, 2, 1), B256, 0, stream>>>(xg, gate_w1, gate_b1, g1, Gn, 128, 256, 0, 0);
    gate2_kernel<<<dim3(8), B256, 0, stream>>>(g1, gate_w2, gate_b2, gatev);
    softmax2048_kernel<<<dim3(1), B256, 0, stream>>>(gatev);
    gemm_kernel<0, 1><<<dim3(32, 4, 1), B256, 0, stream>>>(xg, tr_w, tr_b, ctxb, Gn, 256, 256, 0, 0);
    wsum_kernel<<<dim3(8), B256, 0, stream>>>(gatev, ctxb, pooled);
    head_kernel<<<dim3(1), B256, 0, stream>>>(pooled, head_w, head_b, (float*)d_out);
}

// Round 2
// 365.700 us; speedup vs baseline: 2.6199x; 2.6199x over previous
//
#include <hip/hip_runtime.h>
#include <hip/hip_bf16.h>
#include <cmath>
#include <cstdint>

typedef unsigned int u32;
typedef unsigned char u8;
typedef unsigned short ushort;
typedef __attribute__((ext_vector_type(8))) short short8;
typedef __attribute__((ext_vector_type(4))) float f32x4;
typedef __attribute__((ext_vector_type(4))) unsigned short us4;

#define Gn 2048
#define Hd 256

static __device__ __forceinline__ ushort f2bf(float x) {
    __hip_bfloat16 b = __float2bfloat16(x);
    return *reinterpret_cast<ushort*>(&b);
}

// ---------------------------------------------------------------------------
// Parallel mask dtype detection. 64 blocks x 256 threads x 16B = 256KB scan.
// cnt[0]: nonzero bytes at offset%4==0; cnt[1]: nonzero at other offsets.
// int32 -> c0>0,c123==0 ; int8 -> both>0 ; f32 -> c0==0,c123>0
// ---------------------------------------------------------------------------
__global__ __launch_bounds__(256) void detect2_kernel(const u8* __restrict__ src,
                                                      int* __restrict__ cnt) {
    const int idx = blockIdx.x * 256 + threadIdx.x;
    const uint4 w = ((const uint4*)src)[idx];
    int c0 = ((w.x & 0xffu) ? 1 : 0) + ((w.y & 0xffu) ? 1 : 0) +
             ((w.z & 0xffu) ? 1 : 0) + ((w.w & 0xffu) ? 1 : 0);
    int c1 = ((w.x & 0xffffff00u) ? 1 : 0) + ((w.y & 0xffffff00u) ? 1 : 0) +
             ((w.z & 0xffffff00u) ? 1 : 0) + ((w.w & 0xffffff00u) ? 1 : 0);
    #pragma unroll
    for (int o = 1; o < 64; o <<= 1) { c0 += __shfl_xor(c0, o); c1 += __shfl_xor(c1, o); }
    if ((threadIdx.x & 63) == 0) {
        if (c0) atomicAdd(&cnt[0], c0);
        if (c1) atomicAdd(&cnt[1], c1);
    }
}

// pack mask[rows][cols] (True=attend) into bitmask words [rows][cols/32]
__global__ void pack_mask_kernel(const u8* __restrict__ src, const int* __restrict__ cnt,
                                 u32* __restrict__ bits, int nwords_per_row, int ncols) {
    int idx = blockIdx.x * 256 + threadIdx.x;
    int row = idx / nwords_per_row;
    int w = idx - row * nwords_per_row;
    const int f = (cnt[0] > 0) ? ((cnt[1] > 0) ? 1 : 0) : 2;
    u32 v = 0;
    if (f == 1) {
        const u8* p = src + (long)row * ncols + w * 32;
        #pragma unroll
        for (int j = 0; j < 32; ++j) v |= (p[j] ? 1u : 0u) << j;
    } else if (f == 0) {
        const int* p = (const int*)src + (long)row * ncols + w * 32;
        #pragma unroll
        for (int j = 0; j < 32; ++j) v |= (p[j] ? 1u : 0u) << j;
    } else {
        const float* p = (const float*)src + (long)row * ncols + w * 32;
        #pragma unroll
        for (int j = 0; j < 32; ++j) v |= (p[j] != 0.f ? 1u : 0u) << j;
    }
    bits[idx] = v;
}

// ---------------------------------------------------------------------------
// fp32 tiled GEMM: C[M,N] (+)= A[M,K] @ B[K,N] (+bias) (+relu)
// 64x64 tile, BK=16, 256 threads, 4x4 microtile/thread.
// OUTMODE 0: plain f32 C (strided by blockIdx.z).
// OUTMODE 1: QKV bf16 epilogue. C base is ushort*; z=0 -> Q [h][2048][32],
//            z=1 -> K [h][2048][32] (at +512K elems), z=2 -> Vt [h][32][2048]
//            (at +1M elems). Feeds MFMA attention fragments directly.
// ---------------------------------------------------------------------------
template <int BETA, int RELU, int OUTMODE>
__global__ __launch_bounds__(256) void gemm_kernel(
    const float* __restrict__ A, const float* __restrict__ B,
    const float* __restrict__ bias, float* __restrict__ C,
    int M, int N, int K, long sB, long sC)
{
    B += (long)blockIdx.z * sB;
    if (OUTMODE == 0) C += (long)blockIdx.z * sC;
    __shared__ float As[16][68];
    __shared__ float Bs[16][68];
    const int tid = threadIdx.x;
    const int tx = tid & 15, ty = tid >> 4;
    const int row0 = blockIdx.x * 64, col0 = blockIdx.y * 64;
    float acc[4][4] = {};
    for (int k0 = 0; k0 < K; k0 += 16) {
        {
            const int r = tid >> 2, c4 = (tid & 3) << 2;
            float4 a = *(const float4*)&A[(long)(row0 + r) * K + k0 + c4];
            As[c4 + 0][r] = a.x; As[c4 + 1][r] = a.y;
            As[c4 + 2][r] = a.z; As[c4 + 3][r] = a.w;
            const int rb = tid >> 4, cb = (tid & 15) << 2;
            *(float4*)&Bs[rb][cb] = *(const float4*)&B[(long)(k0 + rb) * N + col0 + cb];
        }
        __syncthreads();
        #pragma unroll
        for (int k = 0; k < 16; ++k) {
            float4 a4 = *(const float4*)&As[k][ty << 2];
            float4 b4 = *(const float4*)&Bs[k][tx << 2];
            float av[4] = {a4.x, a4.y, a4.z, a4.w};
            float bv[4] = {b4.x, b4.y, b4.z, b4.w};
            #pragma unroll
            for (int i = 0; i < 4; ++i)
                #pragma unroll
                for (int j = 0; j < 4; ++j)
                    acc[i][j] += av[i] * bv[j];
        }
        __syncthreads();
    }
    #pragma unroll
    for (int i = 0; i < 4; ++i) {
        const int r = row0 + (ty << 2) + i;
        float bx[4];
        #pragma unroll
        for (int j = 0; j < 4; ++j)
            bx[j] = acc[i][j] + (bias ? bias[col0 + (tx << 2) + j] : 0.f);
        if (OUTMODE == 1) {
            ushort* ob = (ushort*)C;
            const int z = blockIdx.z;
            const int c0c = col0 + (tx << 2);
            const int h = c0c >> 5, d0 = c0c & 31;
            if (z < 2) {
                us4 pw;
                #pragma unroll
                for (int j = 0; j < 4; ++j) pw[j] = f2bf(bx[j]);
                *(us4*)&ob[z * 524288 + ((h * 2048 + r) << 5) + d0] = pw;
            } else {
                #pragma unroll
                for (int j = 0; j < 4; ++j)
                    ob[1048576 + ((h * 32 + d0 + j) << 11) + r] = f2bf(bx[j]);
            }
            continue;
        }
        if (BETA) {
            float4 old = *(const float4*)&C[(long)r * N + col0 + (tx << 2)];
            bx[0] += old.x; bx[1] += old.y; bx[2] += old.z; bx[3] += old.w;
        }
        if (RELU) {
            #pragma unroll
            for (int j = 0; j < 4; ++j) bx[j] = fmaxf(bx[j], 0.f);
        }
        float4 c4v; c4v.x = bx[0]; c4v.y = bx[1]; c4v.z = bx[2]; c4v.w = bx[3];
        *(float4*)&C[(long)r * N + col0 + (tx << 2)] = c4v;
    }
}

// ---------------------------------------------------------------------------
// LayerNorm over rows of 256 (+optional relu). One wave per row.
// ---------------------------------------------------------------------------
template <int RELU>
__global__ __launch_bounds__(64) void ln_kernel(
    const float* __restrict__ X, const float* __restrict__ gw,
    const float* __restrict__ bw, float* __restrict__ Y)
{
    const int row = blockIdx.x, tid = threadIdx.x;
    const float4 x = *(const float4*)&X[(long)row * 256 + (tid << 2)];
    float s = x.x + x.y + x.z + x.w;
    float s2 = x.x * x.x + x.y * x.y + x.z * x.z + x.w * x.w;
    #pragma unroll
    for (int o = 1; o < 64; o <<= 1) { s += __shfl_xor(s, o); s2 += __shfl_xor(s2, o); }
    const float mean = s * (1.f / 256.f);
    const float var = s2 * (1.f / 256.f) - mean * mean;
    const float rs = rsqrtf(var + 1e-5f);
    const float4 g4 = *(const float4*)&gw[tid << 2];
    const float4 b4 = *(const float4*)&bw[tid << 2];
    float4 y;
    y.x = (x.x - mean) * rs * g4.x + b4.x;
    y.y = (x.y - mean) * rs * g4.y + b4.y;
    y.z = (x.z - mean) * rs * g4.z + b4.z;
    y.w = (x.w - mean) * rs * g4.w + b4.w;
    if (RELU) {
        y.x = fmaxf(y.x, 0.f); y.y = fmaxf(y.y, 0.f);
        y.z = fmaxf(y.z, 0.f); y.w = fmaxf(y.w, 0.f);
    }
    *(float4*)&Y[(long)row * 256 + (tid << 2)] = y;
}

// ---------------------------------------------------------------------------
// MFMA flash attention (bf16 inputs, f32 softmax/acc), fully "swapped":
//   S^T tile = mfma(K_frag, Q_frag): lane q = l&15 -> softmax state is
//   lane-local scalars; keys per lane = (l>>4)*4 + r per 16-key subtile.
//   P -> XOR-swizzled wave-private LDS -> B-frag for
//   ctx^T = mfma(Vt_frag, P_frag): rescale + final divide also lane-local.
// K-split x2: wave0 keys [0,1024), wave1 [1024,2048), LDS merge.
// Block = 128 threads (2 waves) = one (head, 16-q tile). Grid (8, 128).
// K/V/Vt read direct from global (L2-resident ~1MB each; no staging).
// Exact where(mask, s, -1e9) semantics incl. all-masked rows -> uniform.
// ---------------------------------------------------------------------------
__global__ __launch_bounds__(128) void attn_mfma_kernel(
    const ushort* __restrict__ qkvb, const u32* __restrict__ maskbits,
    float* __restrict__ ctx)
{
    const ushort* qb = qkvb;
    const ushort* kb = qkvb + 524288;
    const ushort* vt = qkvb + 1048576;
    const int h = blockIdx.x, qt = blockIdx.y;
    const int wv = threadIdx.x >> 6;
    const int l = threadIdx.x & 63;
    const int lq = l & 15;      // this lane's q row (local)
    const int lg = l >> 4;      // lane group
    const int qglob = qt * 16 + lq;
    const float scale = 0.17677669529663687f; // 1/sqrt(32)

    __shared__ __align__(16) ushort Pl[2][1024];
    __shared__ float Mm[16], Ml[16], Macc[64][8];

    // Q B-frag: lane supplies Q[q=l&15][d=(l>>4)*8 + j]
    const short8 qf = *(const short8*)&qb[((h * 2048 + qglob) << 5) + lg * 8];

    float m = -INFINITY, lsum = 0.f;
    f32x4 acc0 = {0.f, 0.f, 0.f, 0.f};
    f32x4 acc1 = {0.f, 0.f, 0.f, 0.f};
    const f32x4 zz = {0.f, 0.f, 0.f, 0.f};

    const int kt0 = wv * 16, kt1 = kt0 + 16;
    for (int kt = kt0; kt < kt1; ++kt) {
        const int kbase = kt * 64;
        // ---- QK^T (swapped): 4 x 16-key subtiles, K-dim = 32 = one MFMA
        f32x4 sacc[4];
        #pragma unroll
        for (int s4 = 0; s4 < 4; ++s4) {
            const short8 kf = *(const short8*)
                &kb[((h * 2048 + kbase + s4 * 16 + lq) << 5) + lg * 8];
            sacc[s4] = __builtin_amdgcn_mfma_f32_16x16x32_bf16(kf, qf, zz, 0, 0, 0);
        }
        // ---- mask + scale (exact where-semantics)
        unsigned long long mw = ~0ull;
        if (maskbits) mw = *(const unsigned long long*)&maskbits[qglob * 64 + kt * 2];
        float sc[16];
        #pragma unroll
        for (int s4 = 0; s4 < 4; ++s4)
            #pragma unroll
            for (int r = 0; r < 4; ++r) {
                const int bit = (int)((mw >> (s4 * 16 + lg * 4 + r)) & 1ull);
                sc[s4 * 4 + r] = bit ? sacc[s4][r] * scale : -1e9f;
            }
        // ---- online softmax (row = lane-local)
        float mt = sc[0];
        #pragma unroll
        for (int i = 1; i < 16; ++i) mt = fmaxf(mt, sc[i]);
        mt = fmaxf(mt, __shfl_xor(mt, 16));
        mt = fmaxf(mt, __shfl_xor(mt, 32));
        const float mn = fmaxf(m, mt);
        const float fac = __expf(m - mn); // -inf first iter -> 0
        float p[16], ps = 0.f;
        #pragma unroll
        for (int i = 0; i < 16; ++i) { p[i] = __expf(sc[i] - mn); ps += p[i]; }
        ps += __shfl_xor(ps, 16);
        ps += __shfl_xor(ps, 32);
        lsum = lsum * fac + ps;
        m = mn;
        #pragma unroll
        for (int j = 0; j < 4; ++j) { acc0[j] *= fac; acc1[j] *= fac; }
        // ---- P -> LDS (bf16, XOR-swizzled [16 q][64 key])
        #pragma unroll
        for (int s4 = 0; s4 < 4; ++s4) {
            const int kb4 = s4 * 16 + lg * 4;
            us4 pw;
            #pragma unroll
            for (int r = 0; r < 4; ++r) pw[r] = f2bf(p[s4 * 4 + r]);
            *(us4*)&Pl[wv][lq * 64 + (((kb4 >> 3) ^ (lq & 7)) << 3) + (kb4 & 7)] = pw;
        }
        // ---- PV (swapped): ctx^T += Vt_frag @ P_frag, 2 key-chunks x 2 d-halves
        #pragma unroll
        for (int c = 0; c < 2; ++c) {
            const short8 pf = *(const short8*)
                &Pl[wv][lq * 64 + (((c * 4 + lg) ^ (lq & 7)) << 3)];
            const short8 vf0 = *(const short8*)
                &vt[((h * 32 + lq) << 11) + kbase + c * 32 + lg * 8];
            acc0 = __builtin_amdgcn_mfma_f32_16x16x32_bf16(vf0, pf, acc0, 0, 0, 0);
            const short8 vf1 = *(const short8*)
                &vt[((h * 32 + 16 + lq) << 11) + kbase + c * 32 + lg * 8];
            acc1 = __builtin_amdgcn_mfma_f32_16x16x32_bf16(vf1, pf, acc1, 0, 0, 0);
        }
    }

    // ---- k-split merge (wave1 -> LDS, wave0 combines + stores)
    if (wv == 1) {
        if (l < 16) { Mm[l] = m; Ml[l] = lsum; }
        #pragma unroll
        for (int j = 0; j < 4; ++j) { Macc[l][j] = acc0[j]; Macc[l][4 + j] = acc1[j]; }
    }
    __syncthreads();
    if (wv == 0) {
        const float m1 = Mm[lq], l1 = Ml[lq];
        const float M = fmaxf(m, m1);
        const float f0 = __expf(m - M), f1 = __expf(m1 - M);
        const float inv = 1.f / (lsum * f0 + l1 * f1);
        float* orow = &ctx[qglob * 256 + h * 32];
        #pragma unroll
        for (int r = 0; r < 4; ++r) {
            orow[lg * 4 + r] = (acc0[r] * f0 + Macc[l][r] * f1) * inv;
            orow[16 + lg * 4 + r] = (acc1[r] * f0 + Macc[l][4 + r] * f1) * inv;
        }
    }
}

// ---------------------------------------------------------------------------
// Aggregation tail
// ---------------------------------------------------------------------------
__global__ __launch_bounds__(256) void gate2_kernel(
    const float* __restrict__ g1, const float* __restrict__ w2,
    const float* __restrict__ b2, float* __restrict__ gv)
{
    int g = blockIdx.x * 256 + threadIdx.x;
    float s = 0.f;
    #pragma unroll
    for (int k = 0; k < 128; k += 4) {
        float4 x = *(const float4*)&g1[(long)g * 128 + k];
        float4 w = *(const float4*)&w2[k];
        s += x.x * w.x + x.y * w.y + x.z * w.z + x.w * w.w;
    }
    gv[g] = s + b2[0];
}

__global__ __launch_bounds__(256) void softmax2048_kernel(float* __restrict__ gv) {
    __shared__ float red[4];
    const int tid = threadIdx.x;
    float v[8];
    float m = -INFINITY;
    #pragma unroll
    for (int i = 0; i < 8; ++i) { v[i] = gv[tid + (i << 8)]; m = fmaxf(m, v[i]); }
    #pragma unroll
    for (int o = 1; o < 64; o <<= 1) m = fmaxf(m, __shfl_xor(m, o));
    if ((tid & 63) == 0) red[tid >> 6] = m;
    __syncthreads();
    m = fmaxf(fmaxf(red[0], red[1]), fmaxf(red[2], red[3]));
    __syncthreads();
    float s = 0.f;
    #pragma unroll
    for (int i = 0; i < 8; ++i) { v[i] = __expf(v[i] - m); s += v[i]; }
    #pragma unroll
    for (int o = 1; o < 64; o <<= 1) s += __shfl_xor(s, o);
    if ((tid & 63) == 0) red[tid >> 6] = s;
    __syncthreads();
    s = red[0] + red[1] + red[2] + red[3];
    const float inv = 1.f / s;
    #pragma unroll
    for (int i = 0; i < 8; ++i) gv[tid + (i << 8)] = v[i] * inv;
}

__global__ __launch_bounds__(256) void wsum_kernel(
    const float* __restrict__ a, const float* __restrict__ t, float* __restrict__ pooled)
{
    __shared__ float red[8][32];
    const int tid = threadIdx.x;
    const int col = blockIdx.x * 32 + (tid & 31);
    const int rg = tid >> 5;
    float s = 0.f;
    for (int r = rg; r < Gn; r += 8) s += a[r] * t[(long)r * 256 + col];
    red[rg][tid & 31] = s;
    __syncthreads();
    if (rg == 0) {
        float tot = 0.f;
        #pragma unroll
        for (int i = 0; i < 8; ++i) tot += red[i][tid & 31];
        pooled[col] = tot;
    }
}

__global__ __launch_bounds__(256) void head_kernel(
    const float* __restrict__ pooled, const float* __restrict__ hw,
    const float* __restrict__ hb, float* __restrict__ out)
{
    __shared__ float red0[4], red1[4];
    const int tid = threadIdx.x;
    const float p = pooled[tid];
    float s0 = p * hw[tid * 2 + 0];
    float s1 = p * hw[tid * 2 + 1];
    #pragma unroll
    for (int o = 1; o < 64; o <<= 1) { s0 += __shfl_xor(s0, o); s1 += __shfl_xor(s1, o); }
    if ((tid & 63) == 0) { red0[tid >> 6] = s0; red1[tid >> 6] = s1; }
    __syncthreads();
    if (tid == 0) {
        out[0] = red0[0] + red0[1] + red0[2] + red0[3] + hb[0];
        out[1] = red1[0] + red1[1] + red1[2] + red1[3] + hb[1];
    }
}

// ---------------------------------------------------------------------------
extern "C" void kernel_launch(void* const* d_in, const int* in_sizes, int n_in,
                              void* d_out, int out_size, void* d_ws, size_t ws_size,
                              hipStream_t stream)
{
    (void)in_sizes; (void)n_in; (void)out_size; (void)ws_size;
    const float* gene_emb = (const float*)d_in[0];
    const float* pre_w1   = (const float*)d_in[3];
    const float* pre_b1   = (const float*)d_in[4];
    const float* pre_w2   = (const float*)d_in[5];
    const float* pre_b2   = (const float*)d_in[6];
    const float* pre_ln_g = (const float*)d_in[7];
    const float* pre_ln_b = (const float*)d_in[8];
    const float* wm       = (const float*)d_in[9];   // [4,4,256,256]
    const float* wsw      = (const float*)d_in[10];  // [3,4,256,256]
    const float* ln_g     = (const float*)d_in[11];  // row 0 (genes)
    const float* ln_b     = (const float*)d_in[12];
    const float* gate_w1  = (const float*)d_in[13];
    const float* gate_b1  = (const float*)d_in[14];
    const float* gate_w2  = (const float*)d_in[15];
    const float* gate_b2  = (const float*)d_in[16];
    const float* tr_w     = (const float*)d_in[17];
    const float* tr_b     = (const float*)d_in[18];
    const float* head_w   = (const float*)d_in[19];
    const float* head_b   = (const float*)d_in[20];
    const u8* adj_pp      = (const u8*)d_in[21];
    const u8* adj_rr      = (const u8*)d_in[22];
    // d_in[1],[2],[23],[24] dead (reaction/metab branches never reach output)

    const long NHf = (long)Gn * Hd; // 524288
    float* tmp0   = (float*)d_ws;
    float* xg     = tmp0 + NHf;
    float* xg1    = xg + NHf;
    float* ctxb   = xg1 + NHf;
    float* g1     = ctxb + NHf;
    float* gatev  = g1 + (long)Gn * 128;
    float* pooled = gatev + Gn;
    int* cnt      = (int*)(pooled + 256);
    u32* bits_pp  = (u32*)(cnt + 64);
    u32* bits_rr  = bits_pp + (long)Gn * 64;
    ushort* qkvb  = (ushort*)(bits_rr + (long)Gn * 64); // 3x512K bf16

    const long W1 = 65536;
    const long W44 = 4 * W1;

    dim3 B256(256), B64g(2048), T64(64), B128(128);
    dim3 attn_grid(8, 128);

    // mask prep
    hipMemsetAsync((void*)cnt, 0, 2 * sizeof(int), stream);
    detect2_kernel<<<dim3(64), B256, 0, stream>>>(adj_pp, cnt);
    pack_mask_kernel<<<dim3(512), B256, 0, stream>>>(adj_pp, cnt, bits_pp, 64, 2048);
    pack_mask_kernel<<<dim3(512), B256, 0, stream>>>(adj_rr, cnt, bits_rr, 64, 2048);

    // preprocessor: xg = relu(LN(relu(LN(gene@w1+b1))@w2+b2))
    gemm_kernel<0, 0, 0><<<dim3(32, 4, 1), B256, 0, stream>>>(gene_emb, pre_w1, pre_b1, tmp0, Gn, 256, 256, 0, 0);
    ln_kernel<1><<<B64g, T64, 0, stream>>>(tmp0, pre_ln_g, pre_ln_b, xg);
    gemm_kernel<0, 0, 0><<<dim3(32, 4, 1), B256, 0, stream>>>(xg, pre_w2, pre_b2, tmp0, Gn, 256, 256, 0, 0);
    ln_kernel<1><<<B64g, T64, 0, stream>>>(tmp0, pre_ln_g, pre_ln_b, xg);

    hipMemcpyAsync(xg1, xg, NHf * sizeof(float), hipMemcpyDeviceToDevice, stream);

    // M block, edge type 0 (adj_pp)
    gemm_kernel<0, 0, 1><<<dim3(32, 4, 3), B256, 0, stream>>>(xg, wm + 0 * W44, nullptr, (float*)qkvb, Gn, 256, 256, W1, 0);
    attn_mfma_kernel<<<attn_grid, B128, 0, stream>>>(qkvb, bits_pp, ctxb);
    gemm_kernel<1, 0, 0><<<dim3(32, 4, 1), B256, 0, stream>>>(ctxb, wm + 0 * W44 + 3 * W1, nullptr, xg1, Gn, 256, 256, 0, 0);

    // M block, edge type 1 (adj_rr) — qkv from ORIGINAL xg
    gemm_kernel<0, 0, 1><<<dim3(32, 4, 3), B256, 0, stream>>>(xg, wm + 1 * W44, nullptr, (float*)qkvb, Gn, 256, 256, W1, 0);
    attn_mfma_kernel<<<attn_grid, B128, 0, stream>>>(qkvb, bits_rr, ctxb);
    gemm_kernel<1, 0, 0><<<dim3(32, 4, 1), B256, 0, stream>>>(ctxb, wm + 1 * W44 + 3 * W1, nullptr, xg1, Gn, 256, 256, 0, 0);

    // S block (full self-attn on xg1)
    gemm_kernel<0, 0, 1><<<dim3(32, 4, 3), B256, 0, stream>>>(xg1, wsw, nullptr, (float*)qkvb, Gn, 256, 256, W1, 0);
    attn_mfma_kernel<<<attn_grid, B128, 0, stream>>>(qkvb, nullptr, ctxb);
    gemm_kernel<1, 0, 0><<<dim3(32, 4, 1), B256, 0, stream>>>(ctxb, wsw + 3 * W1, nullptr, xg1, Gn, 256, 256, 0, 0);

    // final LN (gene branch)
    ln_kernel<0><<<B64g, T64, 0, stream>>>(xg1, ln_g, ln_b, xg);

    // aggregation
    gemm_kernel<0, 1, 0><<<dim3(32, 2, 1), B256, 0, stream>>>(xg, gate_w1, gate_b1, g1, Gn, 128, 256, 0, 0);
    gate2_kernel<<<dim3(8), B256, 0, stream>>>(g1, gate_w2, gate_b2, gatev);
    softmax2048_kernel<<<dim3(1), B256, 0, stream>>>(gatev);
    gemm_kernel<0, 1, 0><<<dim3(32, 4, 1), B256, 0, stream>>>(xg, tr_w, tr_b, ctxb, Gn, 256, 256, 0, 0);
    wsum_kernel<<<dim3(8), B256, 0, stream>>>(gatev, ctxb, pooled);
    head_kernel<<<dim3(1), B256, 0, stream>>>(pooled, head_w, head_b, (float*)d_out);
}

// Round 3
// 311.584 us; speedup vs baseline: 3.0749x; 1.1737x over previous
//
#include <hip/hip_runtime.h>
#include <hip/hip_bf16.h>
#include <cmath>
#include <cstdint>

typedef unsigned int u32;
typedef unsigned char u8;
typedef unsigned short ushort;
typedef __attribute__((ext_vector_type(8))) short short8;
typedef __attribute__((ext_vector_type(4))) float f32x4;
typedef __attribute__((ext_vector_type(4))) unsigned short us4;

#define Gn 2048
#define Hd 256

static __device__ __forceinline__ ushort f2bf(float x) {
    __hip_bfloat16 b = __float2bfloat16(x);
    return *reinterpret_cast<ushort*>(&b);
}

// ---------------------------------------------------------------------------
// Parallel mask dtype detection. 64 blocks x 256 threads x 16B = 256KB scan.
// cnt[0]: nonzero bytes at offset%4==0; cnt[1]: nonzero at other offsets.
// int32 -> c0>0,c123==0 ; int8 -> both>0 ; f32 -> c0==0,c123>0
// ---------------------------------------------------------------------------
__global__ __launch_bounds__(256) void detect2_kernel(const u8* __restrict__ src,
                                                      int* __restrict__ cnt) {
    const int idx = blockIdx.x * 256 + threadIdx.x;
    const uint4 w = ((const uint4*)src)[idx];
    int c0 = ((w.x & 0xffu) ? 1 : 0) + ((w.y & 0xffu) ? 1 : 0) +
             ((w.z & 0xffu) ? 1 : 0) + ((w.w & 0xffu) ? 1 : 0);
    int c1 = ((w.x & 0xffffff00u) ? 1 : 0) + ((w.y & 0xffffff00u) ? 1 : 0) +
             ((w.z & 0xffffff00u) ? 1 : 0) + ((w.w & 0xffffff00u) ? 1 : 0);
    #pragma unroll
    for (int o = 1; o < 64; o <<= 1) { c0 += __shfl_xor(c0, o); c1 += __shfl_xor(c1, o); }
    if ((threadIdx.x & 63) == 0) {
        if (c0) atomicAdd(&cnt[0], c0);
        if (c1) atomicAdd(&cnt[1], c1);
    }
}

// pack mask[rows][cols] (True=attend) into bitmask words [rows][cols/32].
// Vectorized: uint4 loads; per-u32 byte-nonzero -> 4 bits via bit trick.
__global__ __launch_bounds__(256) void pack_mask_kernel(
    const u8* __restrict__ src, const int* __restrict__ cnt,
    u32* __restrict__ bits, int nwords_per_row, int ncols)
{
    const int idx = blockIdx.x * 256 + threadIdx.x;
    const int row = idx / nwords_per_row;
    const int w = idx - row * nwords_per_row;
    const int f = (cnt[0] > 0) ? ((cnt[1] > 0) ? 1 : 0) : 2;
    u32 v = 0;
    if (f == 1) {
        const uint4* p = (const uint4*)(src + (long)row * ncols + w * 32);
        const uint4 q0 = p[0], q1 = p[1];
        const u32 ws8[8] = {q0.x, q0.y, q0.z, q0.w, q1.x, q1.y, q1.z, q1.w};
        #pragma unroll
        for (int j = 0; j < 8; ++j) {
            const u32 x = ws8[j];
            const u32 m = (((x & 0x7f7f7f7fu) + 0x7f7f7f7fu) | x) & 0x80808080u;
            const u32 b4 = ((m >> 7) & 1u) | ((m >> 14) & 2u) |
                           ((m >> 21) & 4u) | ((m >> 28) & 8u);
            v |= b4 << (j * 4);
        }
    } else if (f == 0) {
        const uint4* p = (const uint4*)((const int*)src + (long)row * ncols + w * 32);
        #pragma unroll
        for (int j = 0; j < 8; ++j) {
            const uint4 q = p[j];
            v |= (q.x ? 1u : 0u) << (j * 4 + 0);
            v |= (q.y ? 1u : 0u) << (j * 4 + 1);
            v |= (q.z ? 1u : 0u) << (j * 4 + 2);
            v |= (q.w ? 1u : 0u) << (j * 4 + 3);
        }
    } else {
        const uint4* p = (const uint4*)((const float*)src + (long)row * ncols + w * 32);
        #pragma unroll
        for (int j = 0; j < 8; ++j) {
            const uint4 q = p[j];
            v |= ((q.x & 0x7fffffffu) ? 1u : 0u) << (j * 4 + 0);
            v |= ((q.y & 0x7fffffffu) ? 1u : 0u) << (j * 4 + 1);
            v |= ((q.z & 0x7fffffffu) ? 1u : 0u) << (j * 4 + 2);
            v |= ((q.w & 0x7fffffffu) ? 1u : 0u) << (j * 4 + 3);
        }
    }
    bits[idx] = v;
}

// ---------------------------------------------------------------------------
// fp32 tiled GEMM: C[M,N] (+)= A[M,K] @ B[K,N] (+bias) (+relu)
// 32x64 tile, BK=16, 256 threads, 2x4 microtile/thread -> 256 blocks for
// 2048x256 (1 block/CU; z=3 QKV variant gets 3/CU).
// OUTMODE 0: plain f32 C (strided by blockIdx.z).
// OUTMODE 1: QKV bf16 epilogue. C base is ushort*; z=0 -> Q [h][2048][32],
//            z=1 -> K (+512K elems), z=2 -> Vt [h][32][2048] (+1M elems).
// ---------------------------------------------------------------------------
template <int BETA, int RELU, int OUTMODE>
__global__ __launch_bounds__(256) void gemm_kernel(
    const float* __restrict__ A, const float* __restrict__ B,
    const float* __restrict__ bias, float* __restrict__ C,
    int M, int N, int K, long sB, long sC)
{
    B += (long)blockIdx.z * sB;
    if (OUTMODE == 0) C += (long)blockIdx.z * sC;
    __shared__ float As[16][36];
    __shared__ float Bs[16][68];
    const int tid = threadIdx.x;
    const int tx = tid & 15, ty = tid >> 4;
    const int row0 = blockIdx.x * 32, col0 = blockIdx.y * 64;
    float acc[2][4] = {};
    for (int k0 = 0; k0 < K; k0 += 16) {
        if (tid < 128) {
            const int r = tid >> 2, c4 = (tid & 3) << 2;
            float4 a = *(const float4*)&A[(long)(row0 + r) * K + k0 + c4];
            As[c4 + 0][r] = a.x; As[c4 + 1][r] = a.y;
            As[c4 + 2][r] = a.z; As[c4 + 3][r] = a.w;
        }
        {
            const int rb = tid >> 4, cb = (tid & 15) << 2;
            *(float4*)&Bs[rb][cb] = *(const float4*)&B[(long)(k0 + rb) * N + col0 + cb];
        }
        __syncthreads();
        #pragma unroll
        for (int k = 0; k < 16; ++k) {
            const float a0 = As[k][ty * 2 + 0];
            const float a1 = As[k][ty * 2 + 1];
            const float4 b4 = *(const float4*)&Bs[k][tx << 2];
            acc[0][0] += a0 * b4.x; acc[0][1] += a0 * b4.y;
            acc[0][2] += a0 * b4.z; acc[0][3] += a0 * b4.w;
            acc[1][0] += a1 * b4.x; acc[1][1] += a1 * b4.y;
            acc[1][2] += a1 * b4.z; acc[1][3] += a1 * b4.w;
        }
        __syncthreads();
    }
    #pragma unroll
    for (int i = 0; i < 2; ++i) {
        const int r = row0 + ty * 2 + i;
        float bx[4];
        #pragma unroll
        for (int j = 0; j < 4; ++j)
            bx[j] = acc[i][j] + (bias ? bias[col0 + (tx << 2) + j] : 0.f);
        if (OUTMODE == 1) {
            ushort* ob = (ushort*)C;
            const int z = blockIdx.z;
            const int c0c = col0 + (tx << 2);
            const int h = c0c >> 5, d0 = c0c & 31;
            if (z < 2) {
                us4 pw;
                #pragma unroll
                for (int j = 0; j < 4; ++j) pw[j] = f2bf(bx[j]);
                *(us4*)&ob[z * 524288 + ((h * 2048 + r) << 5) + d0] = pw;
            } else {
                #pragma unroll
                for (int j = 0; j < 4; ++j)
                    ob[1048576 + ((h * 32 + d0 + j) << 11) + r] = f2bf(bx[j]);
            }
            continue;
        }
        if (BETA) {
            float4 old = *(const float4*)&C[(long)r * N + col0 + (tx << 2)];
            bx[0] += old.x; bx[1] += old.y; bx[2] += old.z; bx[3] += old.w;
        }
        if (RELU) {
            #pragma unroll
            for (int j = 0; j < 4; ++j) bx[j] = fmaxf(bx[j], 0.f);
        }
        float4 c4v; c4v.x = bx[0]; c4v.y = bx[1]; c4v.z = bx[2]; c4v.w = bx[3];
        *(float4*)&C[(long)r * N + col0 + (tx << 2)] = c4v;
    }
}

// ---------------------------------------------------------------------------
// LayerNorm over rows of 256 (+optional relu) (+optional duplicate store).
// One wave per row.
// ---------------------------------------------------------------------------
template <int RELU, int DUP>
__global__ __launch_bounds__(64) void ln_kernel(
    const float* __restrict__ X, const float* __restrict__ gw,
    const float* __restrict__ bw, float* __restrict__ Y, float* __restrict__ Y2)
{
    const int row = blockIdx.x, tid = threadIdx.x;
    const float4 x = *(const float4*)&X[(long)row * 256 + (tid << 2)];
    float s = x.x + x.y + x.z + x.w;
    float s2 = x.x * x.x + x.y * x.y + x.z * x.z + x.w * x.w;
    #pragma unroll
    for (int o = 1; o < 64; o <<= 1) { s += __shfl_xor(s, o); s2 += __shfl_xor(s2, o); }
    const float mean = s * (1.f / 256.f);
    const float var = s2 * (1.f / 256.f) - mean * mean;
    const float rs = rsqrtf(var + 1e-5f);
    const float4 g4 = *(const float4*)&gw[tid << 2];
    const float4 b4 = *(const float4*)&bw[tid << 2];
    float4 y;
    y.x = (x.x - mean) * rs * g4.x + b4.x;
    y.y = (x.y - mean) * rs * g4.y + b4.y;
    y.z = (x.z - mean) * rs * g4.z + b4.z;
    y.w = (x.w - mean) * rs * g4.w + b4.w;
    if (RELU) {
        y.x = fmaxf(y.x, 0.f); y.y = fmaxf(y.y, 0.f);
        y.z = fmaxf(y.z, 0.f); y.w = fmaxf(y.w, 0.f);
    }
    *(float4*)&Y[(long)row * 256 + (tid << 2)] = y;
    if (DUP) *(float4*)&Y2[(long)row * 256 + (tid << 2)] = y;
}

// ---------------------------------------------------------------------------
// MFMA flash attention (bf16 inputs, f32 softmax/acc), fully "swapped":
//   S^T tile = mfma(K_frag, Q_frag): lane q = l&15 -> softmax state is
//   lane-local scalars. P -> XOR-swizzled wave-private LDS -> B-frag for
//   ctx^T = mfma(Vt_frag, P_frag). K-split x2 over 2 waves, LDS merge.
// Block = 128 threads = one (head, 16-q tile). Grid (8, 128).
// K/V read direct from global (L2-resident). Exact where(mask,s,-1e9).
// ---------------------------------------------------------------------------
__global__ __launch_bounds__(128) void attn_mfma_kernel(
    const ushort* __restrict__ qkvb, const u32* __restrict__ maskbits,
    float* __restrict__ ctx)
{
    const ushort* qb = qkvb;
    const ushort* kb = qkvb + 524288;
    const ushort* vt = qkvb + 1048576;
    const int h = blockIdx.x, qt = blockIdx.y;
    const int wv = threadIdx.x >> 6;
    const int l = threadIdx.x & 63;
    const int lq = l & 15;      // this lane's q row (local)
    const int lg = l >> 4;      // lane group
    const int qglob = qt * 16 + lq;
    const float scale = 0.17677669529663687f; // 1/sqrt(32)

    __shared__ __align__(16) ushort Pl[2][1024];
    __shared__ float Mm[16], Ml[16], Macc[64][8];

    const short8 qf = *(const short8*)&qb[((h * 2048 + qglob) << 5) + lg * 8];

    float m = -INFINITY, lsum = 0.f;
    f32x4 acc0 = {0.f, 0.f, 0.f, 0.f};
    f32x4 acc1 = {0.f, 0.f, 0.f, 0.f};
    const f32x4 zz = {0.f, 0.f, 0.f, 0.f};

    const int kt0 = wv * 16, kt1 = kt0 + 16;
    for (int kt = kt0; kt < kt1; ++kt) {
        const int kbase = kt * 64;
        f32x4 sacc[4];
        #pragma unroll
        for (int s4 = 0; s4 < 4; ++s4) {
            const short8 kf = *(const short8*)
                &kb[((h * 2048 + kbase + s4 * 16 + lq) << 5) + lg * 8];
            sacc[s4] = __builtin_amdgcn_mfma_f32_16x16x32_bf16(kf, qf, zz, 0, 0, 0);
        }
        unsigned long long mw = ~0ull;
        if (maskbits) mw = *(const unsigned long long*)&maskbits[qglob * 64 + kt * 2];
        float sc[16];
        #pragma unroll
        for (int s4 = 0; s4 < 4; ++s4)
            #pragma unroll
            for (int r = 0; r < 4; ++r) {
                const int bit = (int)((mw >> (s4 * 16 + lg * 4 + r)) & 1ull);
                sc[s4 * 4 + r] = bit ? sacc[s4][r] * scale : -1e9f;
            }
        float mt = sc[0];
        #pragma unroll
        for (int i = 1; i < 16; ++i) mt = fmaxf(mt, sc[i]);
        mt = fmaxf(mt, __shfl_xor(mt, 16));
        mt = fmaxf(mt, __shfl_xor(mt, 32));
        const float mn = fmaxf(m, mt);
        const float fac = __expf(m - mn); // -inf first iter -> 0
        float p[16], ps = 0.f;
        #pragma unroll
        for (int i = 0; i < 16; ++i) { p[i] = __expf(sc[i] - mn); ps += p[i]; }
        ps += __shfl_xor(ps, 16);
        ps += __shfl_xor(ps, 32);
        lsum = lsum * fac + ps;
        m = mn;
        #pragma unroll
        for (int j = 0; j < 4; ++j) { acc0[j] *= fac; acc1[j] *= fac; }
        #pragma unroll
        for (int s4 = 0; s4 < 4; ++s4) {
            const int kb4 = s4 * 16 + lg * 4;
            us4 pw;
            #pragma unroll
            for (int r = 0; r < 4; ++r) pw[r] = f2bf(p[s4 * 4 + r]);
            *(us4*)&Pl[wv][lq * 64 + (((kb4 >> 3) ^ (lq & 7)) << 3) + (kb4 & 7)] = pw;
        }
        #pragma unroll
        for (int c = 0; c < 2; ++c) {
            const short8 pf = *(const short8*)
                &Pl[wv][lq * 64 + (((c * 4 + lg) ^ (lq & 7)) << 3)];
            const short8 vf0 = *(const short8*)
                &vt[((h * 32 + lq) << 11) + kbase + c * 32 + lg * 8];
            acc0 = __builtin_amdgcn_mfma_f32_16x16x32_bf16(vf0, pf, acc0, 0, 0, 0);
            const short8 vf1 = *(const short8*)
                &vt[((h * 32 + 16 + lq) << 11) + kbase + c * 32 + lg * 8];
            acc1 = __builtin_amdgcn_mfma_f32_16x16x32_bf16(vf1, pf, acc1, 0, 0, 0);
        }
    }

    if (wv == 1) {
        if (l < 16) { Mm[l] = m; Ml[l] = lsum; }
        #pragma unroll
        for (int j = 0; j < 4; ++j) { Macc[l][j] = acc0[j]; Macc[l][4 + j] = acc1[j]; }
    }
    __syncthreads();
    if (wv == 0) {
        const float m1 = Mm[lq], l1 = Ml[lq];
        const float M = fmaxf(m, m1);
        const float f0 = __expf(m - M), f1 = __expf(m1 - M);
        const float inv = 1.f / (lsum * f0 + l1 * f1);
        float* orow = &ctx[qglob * 256 + h * 32];
        #pragma unroll
        for (int r = 0; r < 4; ++r) {
            orow[lg * 4 + r] = (acc0[r] * f0 + Macc[l][r] * f1) * inv;
            orow[16 + lg * 4 + r] = (acc1[r] * f0 + Macc[l][4 + r] * f1) * inv;
        }
    }
}

// ---------------------------------------------------------------------------
// Aggregation tail
// ---------------------------------------------------------------------------
__global__ __launch_bounds__(256) void gate2_kernel(
    const float* __restrict__ g1, const float* __restrict__ w2,
    const float* __restrict__ b2, float* __restrict__ gv)
{
    int g = blockIdx.x * 256 + threadIdx.x;
    float s = 0.f;
    #pragma unroll
    for (int k = 0; k < 128; k += 4) {
        float4 x = *(const float4*)&g1[(long)g * 128 + k];
        float4 w = *(const float4*)&w2[k];
        s += x.x * w.x + x.y * w.y + x.z * w.z + x.w * w.w;
    }
    gv[g] = s + b2[0];
}

__global__ __launch_bounds__(256) void softmax2048_kernel(float* __restrict__ gv) {
    __shared__ float red[4];
    const int tid = threadIdx.x;
    float v[8];
    float m = -INFINITY;
    #pragma unroll
    for (int i = 0; i < 8; ++i) { v[i] = gv[tid + (i << 8)]; m = fmaxf(m, v[i]); }
    #pragma unroll
    for (int o = 1; o < 64; o <<= 1) m = fmaxf(m, __shfl_xor(m, o));
    if ((tid & 63) == 0) red[tid >> 6] = m;
    __syncthreads();
    m = fmaxf(fmaxf(red[0], red[1]), fmaxf(red[2], red[3]));
    __syncthreads();
    float s = 0.f;
    #pragma unroll
    for (int i = 0; i < 8; ++i) { v[i] = __expf(v[i] - m); s += v[i]; }
    #pragma unroll
    for (int o = 1; o < 64; o <<= 1) s += __shfl_xor(s, o);
    if ((tid & 63) == 0) red[tid >> 6] = s;
    __syncthreads();
    s = red[0] + red[1] + red[2] + red[3];
    const float inv = 1.f / s;
    #pragma unroll
    for (int i = 0; i < 8; ++i) gv[tid + (i << 8)] = v[i] * inv;
}

// partial[b][col] = sum over 16 rows of a[r]*t[r][col]; grid 128 x 256 thr
__global__ __launch_bounds__(256) void wsum_part_kernel(
    const float* __restrict__ a, const float* __restrict__ t,
    float* __restrict__ partial)
{
    const int b = blockIdx.x, col = threadIdx.x;
    const int base = b * 16;
    float s = 0.f;
    #pragma unroll
    for (int i = 0; i < 16; ++i)
        s += a[base + i] * t[(long)(base + i) * 256 + col];
    partial[b * 256 + col] = s;
}

// fused: pooled[col] = sum_b partial[b][col]; out = pooled @ head_w + head_b
__global__ __launch_bounds__(256) void head2_kernel(
    const float* __restrict__ partial, const float* __restrict__ hw,
    const float* __restrict__ hb, float* __restrict__ out)
{
    __shared__ float red0[4], red1[4];
    const int tid = threadIdx.x;
    float p = 0.f;
    #pragma unroll 8
    for (int b = 0; b < 128; ++b) p += partial[b * 256 + tid];
    float s0 = p * hw[tid * 2 + 0];
    float s1 = p * hw[tid * 2 + 1];
    #pragma unroll
    for (int o = 1; o < 64; o <<= 1) { s0 += __shfl_xor(s0, o); s1 += __shfl_xor(s1, o); }
    if ((tid & 63) == 0) { red0[tid >> 6] = s0; red1[tid >> 6] = s1; }
    __syncthreads();
    if (tid == 0) {
        out[0] = red0[0] + red0[1] + red0[2] + red0[3] + hb[0];
        out[1] = red1[0] + red1[1] + red1[2] + red1[3] + hb[1];
    }
}

// ---------------------------------------------------------------------------
extern "C" void kernel_launch(void* const* d_in, const int* in_sizes, int n_in,
                              void* d_out, int out_size, void* d_ws, size_t ws_size,
                              hipStream_t stream)
{
    (void)in_sizes; (void)n_in; (void)out_size; (void)ws_size;
    const float* gene_emb = (const float*)d_in[0];
    const float* pre_w1   = (const float*)d_in[3];
    const float* pre_b1   = (const float*)d_in[4];
    const float* pre_w2   = (const float*)d_in[5];
    const float* pre_b2   = (const float*)d_in[6];
    const float* pre_ln_g = (const float*)d_in[7];
    const float* pre_ln_b = (const float*)d_in[8];
    const float* wm       = (const float*)d_in[9];   // [4,4,256,256]
    const float* wsw      = (const float*)d_in[10];  // [3,4,256,256]
    const float* ln_g     = (const float*)d_in[11];  // row 0 (genes)
    const float* ln_b     = (const float*)d_in[12];
    const float* gate_w1  = (const float*)d_in[13];
    const float* gate_b1  = (const float*)d_in[14];
    const float* gate_w2  = (const float*)d_in[15];
    const float* gate_b2  = (const float*)d_in[16];
    const float* tr_w     = (const float*)d_in[17];
    const float* tr_b     = (const float*)d_in[18];
    const float* head_w   = (const float*)d_in[19];
    const float* head_b   = (const float*)d_in[20];
    const u8* adj_pp      = (const u8*)d_in[21];
    const u8* adj_rr      = (const u8*)d_in[22];
    // d_in[1],[2],[23],[24] dead (reaction/metab branches never reach output)

    const long NHf = (long)Gn * Hd; // 524288
    float* tmp0    = (float*)d_ws;
    float* xg      = tmp0 + NHf;
    float* xg1     = xg + NHf;
    float* ctxb    = xg1 + NHf;
    float* g1      = ctxb + NHf;
    float* gatev   = g1 + (long)Gn * 128;
    float* partial = gatev + Gn;          // 128*256 floats
    int* cnt       = (int*)(partial + 128 * 256);
    u32* bits_pp   = (u32*)(cnt + 64);
    u32* bits_rr   = bits_pp + (long)Gn * 64;
    ushort* qkvb   = (ushort*)(bits_rr + (long)Gn * 64); // 3x512K bf16

    const long W1 = 65536;
    const long W44 = 4 * W1;

    dim3 B256(256), B64g(2048), T64(64), B128(128);
    dim3 attn_grid(8, 128);
    dim3 g2048x256(64, 4, 1), gqkv(64, 4, 3), ggate(64, 2, 1);

    // mask prep
    hipMemsetAsync((void*)cnt, 0, 2 * sizeof(int), stream);
    detect2_kernel<<<dim3(64), B256, 0, stream>>>(adj_pp, cnt);
    pack_mask_kernel<<<dim3(512), B256, 0, stream>>>(adj_pp, cnt, bits_pp, 64, 2048);
    pack_mask_kernel<<<dim3(512), B256, 0, stream>>>(adj_rr, cnt, bits_rr, 64, 2048);

    // preprocessor: xg = relu(LN(relu(LN(gene@w1+b1))@w2+b2)); xg1 = xg
    gemm_kernel<0, 0, 0><<<g2048x256, B256, 0, stream>>>(gene_emb, pre_w1, pre_b1, tmp0, Gn, 256, 256, 0, 0);
    ln_kernel<1, 0><<<B64g, T64, 0, stream>>>(tmp0, pre_ln_g, pre_ln_b, xg, nullptr);
    gemm_kernel<0, 0, 0><<<g2048x256, B256, 0, stream>>>(xg, pre_w2, pre_b2, tmp0, Gn, 256, 256, 0, 0);
    ln_kernel<1, 1><<<B64g, T64, 0, stream>>>(tmp0, pre_ln_g, pre_ln_b, xg, xg1);

    // M block, edge type 0 (adj_pp)
    gemm_kernel<0, 0, 1><<<gqkv, B256, 0, stream>>>(xg, wm + 0 * W44, nullptr, (float*)qkvb, Gn, 256, 256, W1, 0);
    attn_mfma_kernel<<<attn_grid, B128, 0, stream>>>(qkvb, bits_pp, ctxb);
    gemm_kernel<1, 0, 0><<<g2048x256, B256, 0, stream>>>(ctxb, wm + 0 * W44 + 3 * W1, nullptr, xg1, Gn, 256, 256, 0, 0);

    // M block, edge type 1 (adj_rr) — qkv from ORIGINAL xg
    gemm_kernel<0, 0, 1><<<gqkv, B256, 0, stream>>>(xg, wm + 1 * W44, nullptr, (float*)qkvb, Gn, 256, 256, W1, 0);
    attn_mfma_kernel<<<attn_grid, B128, 0, stream>>>(qkvb, bits_rr, ctxb);
    gemm_kernel<1, 0, 0><<<g2048x256, B256, 0, stream>>>(ctxb, wm + 1 * W44 + 3 * W1, nullptr, xg1, Gn, 256, 256, 0, 0);

    // S block (full self-attn on xg1)
    gemm_kernel<0, 0, 1><<<gqkv, B256, 0, stream>>>(xg1, wsw, nullptr, (float*)qkvb, Gn, 256, 256, W1, 0);
    attn_mfma_kernel<<<attn_grid, B128, 0, stream>>>(qkvb, nullptr, ctxb);
    gemm_kernel<1, 0, 0><<<g2048x256, B256, 0, stream>>>(ctxb, wsw + 3 * W1, nullptr, xg1, Gn, 256, 256, 0, 0);

    // final LN (gene branch)
    ln_kernel<0, 0><<<B64g, T64, 0, stream>>>(xg1, ln_g, ln_b, xg, nullptr);

    // aggregation
    gemm_kernel<0, 1, 0><<<ggate, B256, 0, stream>>>(xg, gate_w1, gate_b1, g1, Gn, 128, 256, 0, 0);
    gate2_kernel<<<dim3(8), B256, 0, stream>>>(g1, gate_w2, gate_b2, gatev);
    softmax2048_kernel<<<dim3(1), B256, 0, stream>>>(gatev);
    gemm_kernel<0, 1, 0><<<g2048x256, B256, 0, stream>>>(xg, tr_w, tr_b, ctxb, Gn, 256, 256, 0, 0);
    wsum_part_kernel<<<dim3(128), B256, 0, stream>>>(gatev, ctxb, partial);
    head2_kernel<<<dim3(1), B256, 0, stream>>>(partial, head_w, head_b, (float*)d_out);
}

// Round 4
// 254.786 us; speedup vs baseline: 3.7604x; 1.2229x over previous
//
#include <hip/hip_runtime.h>
#include <hip/hip_bf16.h>
#include <cmath>
#include <cstdint>

typedef unsigned int u32;
typedef unsigned char u8;
typedef unsigned short ushort;
typedef __attribute__((ext_vector_type(8))) short short8;
typedef __attribute__((ext_vector_type(4))) float f32x4;
typedef __attribute__((ext_vector_type(4))) unsigned short us4;

#define Gn 2048
#define Hd 256

static __device__ __forceinline__ ushort f2bf(float x) {
    __hip_bfloat16 b = __float2bfloat16(x);
    return *reinterpret_cast<ushort*>(&b);
}

// ---------------------------------------------------------------------------
// Parallel mask dtype detection (64 blocks x 256 thr x 16B = 256KB scan).
// cnt[0]: nonzero bytes at offset%4==0; cnt[1]: elsewhere.
// int32 -> c0>0,c1==0 ; int8 -> both>0 ; f32 -> c0==0
// ---------------------------------------------------------------------------
__global__ __launch_bounds__(256) void detect2_kernel(const u8* __restrict__ src,
                                                      int* __restrict__ cnt) {
    const int idx = blockIdx.x * 256 + threadIdx.x;
    const uint4 w = ((const uint4*)src)[idx];
    int c0 = ((w.x & 0xffu) ? 1 : 0) + ((w.y & 0xffu) ? 1 : 0) +
             ((w.z & 0xffu) ? 1 : 0) + ((w.w & 0xffu) ? 1 : 0);
    int c1 = ((w.x & 0xffffff00u) ? 1 : 0) + ((w.y & 0xffffff00u) ? 1 : 0) +
             ((w.z & 0xffffff00u) ? 1 : 0) + ((w.w & 0xffffff00u) ? 1 : 0);
    #pragma unroll
    for (int o = 1; o < 64; o <<= 1) { c0 += __shfl_xor(c0, o); c1 += __shfl_xor(c1, o); }
    if ((threadIdx.x & 63) == 0) {
        if (c0) atomicAdd(&cnt[0], c0);
        if (c1) atomicAdd(&cnt[1], c1);
    }
}

// pack mask[rows][cols] (True=attend) into bitmask words [rows][cols/32]
__global__ __launch_bounds__(256) void pack_mask_kernel(
    const u8* __restrict__ src, const int* __restrict__ cnt,
    u32* __restrict__ bits, int nwords_per_row, int ncols)
{
    const int idx = blockIdx.x * 256 + threadIdx.x;
    const int row = idx / nwords_per_row;
    const int w = idx - row * nwords_per_row;
    const int f = (cnt[0] > 0) ? ((cnt[1] > 0) ? 1 : 0) : 2;
    u32 v = 0;
    if (f == 1) {
        const uint4* p = (const uint4*)(src + (long)row * ncols + w * 32);
        const uint4 q0 = p[0], q1 = p[1];
        const u32 ws8[8] = {q0.x, q0.y, q0.z, q0.w, q1.x, q1.y, q1.z, q1.w};
        #pragma unroll
        for (int j = 0; j < 8; ++j) {
            const u32 x = ws8[j];
            const u32 m = (((x & 0x7f7f7f7fu) + 0x7f7f7f7fu) | x) & 0x80808080u;
            const u32 b4 = ((m >> 7) & 1u) | ((m >> 14) & 2u) |
                           ((m >> 21) & 4u) | ((m >> 28) & 8u);
            v |= b4 << (j * 4);
        }
    } else if (f == 0) {
        const uint4* p = (const uint4*)((const int*)src + (long)row * ncols + w * 32);
        #pragma unroll
        for (int j = 0; j < 8; ++j) {
            const uint4 q = p[j];
            v |= (q.x ? 1u : 0u) << (j * 4 + 0);
            v |= (q.y ? 1u : 0u) << (j * 4 + 1);
            v |= (q.z ? 1u : 0u) << (j * 4 + 2);
            v |= (q.w ? 1u : 0u) << (j * 4 + 3);
        }
    } else {
        const uint4* p = (const uint4*)((const float*)src + (long)row * ncols + w * 32);
        #pragma unroll
        for (int j = 0; j < 8; ++j) {
            const uint4 q = p[j];
            v |= ((q.x & 0x7fffffffu) ? 1u : 0u) << (j * 4 + 0);
            v |= ((q.y & 0x7fffffffu) ? 1u : 0u) << (j * 4 + 1);
            v |= ((q.z & 0x7fffffffu) ? 1u : 0u) << (j * 4 + 2);
            v |= ((q.w & 0x7fffffffu) ? 1u : 0u) << (j * 4 + 3);
        }
    }
    bits[idx] = v;
}

// ---------------------------------------------------------------------------
// Weight pre-pass: for each 256-row weight matrix W[k][n], emit transposed
// bf16 split arenas Bt_hi[n][k], Bt_lo[n][k] (slot = 64K ushorts).
// slots: 0 pre_w1, 1 pre_w2, 2-5 wm0 QKVO, 6-9 wm1 QKVO, 10-13 ws0 QKVO,
//        14 gate_w1 (ncols=128), 15 tr_w. Grid (16 slots, 8 k-slabs).
// ---------------------------------------------------------------------------
__global__ __launch_bounds__(256) void preconv_kernel(
    const float* __restrict__ pre_w1, const float* __restrict__ pre_w2,
    const float* __restrict__ wm, const float* __restrict__ wsw,
    const float* __restrict__ gate_w1, const float* __restrict__ tr_w,
    ushort* __restrict__ bt_hi, ushort* __restrict__ bt_lo)
{
    const int slot = blockIdx.x;
    const int k0 = blockIdx.y * 32;
    const float* src; int ncols = 256;
    if (slot == 0) src = pre_w1;
    else if (slot == 1) src = pre_w2;
    else if (slot < 6) src = wm + (long)(slot - 2) * 65536;
    else if (slot < 10) src = wm + (long)(4 + slot - 6) * 65536;
    else if (slot < 14) src = wsw + (long)(slot - 10) * 65536;
    else if (slot == 14) { src = gate_w1; ncols = 128; }
    else src = tr_w;

    __shared__ float T[32][257];
    const int tid = threadIdx.x;
    const int lsh = (ncols == 256) ? 6 : 5;      // float4s per row
    const int tot = 32 << lsh;
    for (int i = tid; i < tot; i += 256) {
        const int kk = i >> lsh, c4 = (i & ((1 << lsh) - 1)) << 2;
        const float4 v = *(const float4*)&src[(long)(k0 + kk) * ncols + c4];
        T[kk][c4 + 0] = v.x; T[kk][c4 + 1] = v.y;
        T[kk][c4 + 2] = v.z; T[kk][c4 + 3] = v.w;
    }
    __syncthreads();
    if (tid < ncols) {
        ushort hb[32], lb[32];
        #pragma unroll
        for (int kk = 0; kk < 32; ++kk) {
            const float x = T[kk][tid];
            const u32 bi = __float_as_uint(x);
            const ushort h = (ushort)(bi >> 16);            // truncated hi
            const float fh = __uint_as_float(bi & 0xffff0000u);
            hb[kk] = h; lb[kk] = f2bf(x - fh);
        }
        ushort* oh = bt_hi + (long)slot * 65536 + tid * 256 + k0;
        ushort* ol = bt_lo + (long)slot * 65536 + tid * 256 + k0;
        #pragma unroll
        for (int q = 0; q < 4; ++q) {
            *(uint4*)&oh[q * 8] = *(const uint4*)&hb[q * 8];
            *(uint4*)&ol[q * 8] = *(const uint4*)&lb[q * 8];
        }
    }
}

// ---------------------------------------------------------------------------
// bf16x3 split-precision MFMA GEMM (~fp32 accurate): C[M,N] (+)= A @ W (+bias)
// A fp32 [M][lda]; W via pre-split/transposed arenas Bt_hi/Bt_lo (slot0;
// slot2 supplies k>=256 for KT=512 — fuses xg1 += ctx0@Wo0 + ctx1@Wo1).
// Tile 32x64, 2 waves, no LDS. Fragments direct from global (L2-resident).
// OUTMODE 1 = QKV bf16 epilogue (Q/K [h][2048][32], Vt [h][32][2048]).
// QKVMODE: 1 = M-block 6-way z (slot 2+z+z/3, buffer z/3); 2 = S-block 3-way.
// ---------------------------------------------------------------------------
template <int BETA, int RELU, int OUTMODE, int QKVMODE, int KT>
__global__ __launch_bounds__(128) void gemm_mfma_kernel(
    const float* __restrict__ A, int lda,
    const ushort* __restrict__ bt_hi, const ushort* __restrict__ bt_lo,
    int slot0, int slot2, const float* __restrict__ bias,
    float* __restrict__ C, int N)
{
    const int tid = threadIdx.x;
    const int wv = tid >> 6, l = tid & 63;
    const int lr = l & 15, lg = l >> 4;
    const int row = blockIdx.x * 32 + wv * 16 + lr;
    const int col0 = blockIdx.y * 64;
    int slot = slot0, zq = 0, buf = 0;
    if (QKVMODE == 1) {
        const int z = blockIdx.z;
        slot = slot0 + z + z / 3; zq = z % 3; buf = z / 3;
    } else if (QKVMODE == 2) {
        const int z = blockIdx.z;
        slot = slot0 + z; zq = z;
    }
    const ushort* bhb = bt_hi + (long)slot * 65536;
    const ushort* blb = bt_lo + (long)slot * 65536;
    const float* arow = A + (long)row * lda;

    const f32x4 z4 = {0.f, 0.f, 0.f, 0.f};
    f32x4 acc[4] = {z4, z4, z4, z4};

    #pragma unroll
    for (int ks = 0; ks < KT / 32; ++ks) {
        const int k0 = ks * 32;
        const ushort* bh; const ushort* bl;
        if (KT == 512 && k0 >= 256) {
            bh = bt_hi + (long)slot2 * 65536 + (k0 - 256);
            bl = bt_lo + (long)slot2 * 65536 + (k0 - 256);
        } else { bh = bhb + k0; bl = blb + k0; }
        float av[8];
        *(float4*)&av[0] = *(const float4*)&arow[k0 + lg * 8];
        *(float4*)&av[4] = *(const float4*)&arow[k0 + lg * 8 + 4];
        short8 ahi, alo;
        #pragma unroll
        for (int j = 0; j < 8; ++j) {
            const u32 bi = __float_as_uint(av[j]);
            ahi[j] = (short)(bi >> 16);
            const float fh = __uint_as_float(bi & 0xffff0000u);
            alo[j] = (short)f2bf(av[j] - fh);
        }
        #pragma unroll
        for (int f = 0; f < 4; ++f) {
            const long bo = (long)(col0 + f * 16 + lr) * 256 + lg * 8;
            const short8 bhi = *(const short8*)&bh[bo];
            const short8 blo = *(const short8*)&bl[bo];
            acc[f] = __builtin_amdgcn_mfma_f32_16x16x32_bf16(ahi, bhi, acc[f], 0, 0, 0);
            acc[f] = __builtin_amdgcn_mfma_f32_16x16x32_bf16(alo, bhi, acc[f], 0, 0, 0);
            acc[f] = __builtin_amdgcn_mfma_f32_16x16x32_bf16(ahi, blo, acc[f], 0, 0, 0);
        }
    }

    #pragma unroll
    for (int f = 0; f < 4; ++f) {
        const int col = col0 + f * 16 + lr;
        const float bv = bias ? bias[col] : 0.f;
        #pragma unroll
        for (int r = 0; r < 4; ++r) {
            const int rr = blockIdx.x * 32 + wv * 16 + lg * 4 + r;
            float v = acc[f][r] + bv;
            if (OUTMODE == 1) {
                ushort* ob = (ushort*)C + (long)buf * 1572864;
                const int h = col >> 5, d = col & 31;
                if (zq < 2) ob[zq * 524288 + ((h * 2048 + rr) << 5) + d] = f2bf(v);
                else        ob[1048576 + ((h * 32 + d) << 11) + rr] = f2bf(v);
            } else {
                if (BETA) v += C[(long)rr * N + col];
                if (RELU) v = fmaxf(v, 0.f);
                C[(long)rr * N + col] = v;
            }
        }
    }
}

// ---------------------------------------------------------------------------
// LayerNorm over rows of 256 (+optional relu) (+optional duplicate store).
// ---------------------------------------------------------------------------
template <int RELU, int DUP>
__global__ __launch_bounds__(64) void ln_kernel(
    const float* __restrict__ X, const float* __restrict__ gw,
    const float* __restrict__ bw, float* __restrict__ Y, float* __restrict__ Y2)
{
    const int row = blockIdx.x, tid = threadIdx.x;
    const float4 x = *(const float4*)&X[(long)row * 256 + (tid << 2)];
    float s = x.x + x.y + x.z + x.w;
    float s2 = x.x * x.x + x.y * x.y + x.z * x.z + x.w * x.w;
    #pragma unroll
    for (int o = 1; o < 64; o <<= 1) { s += __shfl_xor(s, o); s2 += __shfl_xor(s2, o); }
    const float mean = s * (1.f / 256.f);
    const float var = s2 * (1.f / 256.f) - mean * mean;
    const float rs = rsqrtf(var + 1e-5f);
    const float4 g4 = *(const float4*)&gw[tid << 2];
    const float4 b4 = *(const float4*)&bw[tid << 2];
    float4 y;
    y.x = (x.x - mean) * rs * g4.x + b4.x;
    y.y = (x.y - mean) * rs * g4.y + b4.y;
    y.z = (x.z - mean) * rs * g4.z + b4.z;
    y.w = (x.w - mean) * rs * g4.w + b4.w;
    if (RELU) {
        y.x = fmaxf(y.x, 0.f); y.y = fmaxf(y.y, 0.f);
        y.z = fmaxf(y.z, 0.f); y.w = fmaxf(y.w, 0.f);
    }
    *(float4*)&Y[(long)row * 256 + (tid << 2)] = y;
    if (DUP) *(float4*)&Y2[(long)row * 256 + (tid << 2)] = y;
}

// ---------------------------------------------------------------------------
// MFMA flash attention (bf16 in, f32 softmax/acc), swapped operands;
// z-batched: blockIdx.z selects qkv buffer + mask + ctx column block.
// ctx2 row stride = 512 (two attention outputs side by side).
// ---------------------------------------------------------------------------
__global__ __launch_bounds__(128) void attn_mfma_kernel(
    const ushort* __restrict__ qkvb, const u32* __restrict__ mb0,
    const u32* __restrict__ mb1, float* __restrict__ ctx)
{
    const int zb = blockIdx.z;
    const ushort* qb = qkvb + (long)zb * 1572864;
    const ushort* kb = qb + 524288;
    const ushort* vt = qb + 1048576;
    const u32* maskbits = (zb == 0) ? mb0 : mb1;
    const int h = blockIdx.x, qt = blockIdx.y;
    const int wv = threadIdx.x >> 6;
    const int l = threadIdx.x & 63;
    const int lq = l & 15;
    const int lg = l >> 4;
    const int qglob = qt * 16 + lq;
    const float scale = 0.17677669529663687f; // 1/sqrt(32)

    __shared__ __align__(16) ushort Pl[2][1024];
    __shared__ float Mm[16], Ml[16], Macc[64][8];

    const short8 qf = *(const short8*)&qb[((h * 2048 + qglob) << 5) + lg * 8];

    float m = -INFINITY, lsum = 0.f;
    f32x4 acc0 = {0.f, 0.f, 0.f, 0.f};
    f32x4 acc1 = {0.f, 0.f, 0.f, 0.f};
    const f32x4 zz = {0.f, 0.f, 0.f, 0.f};

    const int kt0 = wv * 16, kt1 = kt0 + 16;
    for (int kt = kt0; kt < kt1; ++kt) {
        const int kbase = kt * 64;
        f32x4 sacc[4];
        #pragma unroll
        for (int s4 = 0; s4 < 4; ++s4) {
            const short8 kf = *(const short8*)
                &kb[((h * 2048 + kbase + s4 * 16 + lq) << 5) + lg * 8];
            sacc[s4] = __builtin_amdgcn_mfma_f32_16x16x32_bf16(kf, qf, zz, 0, 0, 0);
        }
        unsigned long long mw = ~0ull;
        if (maskbits) mw = *(const unsigned long long*)&maskbits[qglob * 64 + kt * 2];
        float sc[16];
        #pragma unroll
        for (int s4 = 0; s4 < 4; ++s4)
            #pragma unroll
            for (int r = 0; r < 4; ++r) {
                const int bit = (int)((mw >> (s4 * 16 + lg * 4 + r)) & 1ull);
                sc[s4 * 4 + r] = bit ? sacc[s4][r] * scale : -1e9f;
            }
        float mt = sc[0];
        #pragma unroll
        for (int i = 1; i < 16; ++i) mt = fmaxf(mt, sc[i]);
        mt = fmaxf(mt, __shfl_xor(mt, 16));
        mt = fmaxf(mt, __shfl_xor(mt, 32));
        const float mn = fmaxf(m, mt);
        const float fac = __expf(m - mn);
        float p[16], ps = 0.f;
        #pragma unroll
        for (int i = 0; i < 16; ++i) { p[i] = __expf(sc[i] - mn); ps += p[i]; }
        ps += __shfl_xor(ps, 16);
        ps += __shfl_xor(ps, 32);
        lsum = lsum * fac + ps;
        m = mn;
        #pragma unroll
        for (int j = 0; j < 4; ++j) { acc0[j] *= fac; acc1[j] *= fac; }
        #pragma unroll
        for (int s4 = 0; s4 < 4; ++s4) {
            const int kb4 = s4 * 16 + lg * 4;
            us4 pw;
            #pragma unroll
            for (int r = 0; r < 4; ++r) pw[r] = f2bf(p[s4 * 4 + r]);
            *(us4*)&Pl[wv][lq * 64 + (((kb4 >> 3) ^ (lq & 7)) << 3) + (kb4 & 7)] = pw;
        }
        #pragma unroll
        for (int c = 0; c < 2; ++c) {
            const short8 pf = *(const short8*)
                &Pl[wv][lq * 64 + (((c * 4 + lg) ^ (lq & 7)) << 3)];
            const short8 vf0 = *(const short8*)
                &vt[((h * 32 + lq) << 11) + kbase + c * 32 + lg * 8];
            acc0 = __builtin_amdgcn_mfma_f32_16x16x32_bf16(vf0, pf, acc0, 0, 0, 0);
            const short8 vf1 = *(const short8*)
                &vt[((h * 32 + 16 + lq) << 11) + kbase + c * 32 + lg * 8];
            acc1 = __builtin_amdgcn_mfma_f32_16x16x32_bf16(vf1, pf, acc1, 0, 0, 0);
        }
    }

    if (wv == 1) {
        if (l < 16) { Mm[l] = m; Ml[l] = lsum; }
        #pragma unroll
        for (int j = 0; j < 4; ++j) { Macc[l][j] = acc0[j]; Macc[l][4 + j] = acc1[j]; }
    }
    __syncthreads();
    if (wv == 0) {
        const float m1 = Mm[lq], l1 = Ml[lq];
        const float M = fmaxf(m, m1);
        const float f0 = __expf(m - M), f1 = __expf(m1 - M);
        const float inv = 1.f / (lsum * f0 + l1 * f1);
        float* orow = &ctx[(long)qglob * 512 + zb * 256 + h * 32];
        #pragma unroll
        for (int r = 0; r < 4; ++r) {
            orow[lg * 4 + r] = (acc0[r] * f0 + Macc[l][r] * f1) * inv;
            orow[16 + lg * 4 + r] = (acc1[r] * f0 + Macc[l][4 + r] * f1) * inv;
        }
    }
}

// ---------------------------------------------------------------------------
// Aggregation tail
// ---------------------------------------------------------------------------
__global__ __launch_bounds__(256) void gate2_kernel(
    const float* __restrict__ g1, const float* __restrict__ w2,
    const float* __restrict__ b2, float* __restrict__ gv)
{
    int g = blockIdx.x * 256 + threadIdx.x;
    float s = 0.f;
    #pragma unroll
    for (int k = 0; k < 128; k += 4) {
        float4 x = *(const float4*)&g1[(long)g * 128 + k];
        float4 w = *(const float4*)&w2[k];
        s += x.x * w.x + x.y * w.y + x.z * w.z + x.w * w.w;
    }
    gv[g] = s + b2[0];
}

__global__ __launch_bounds__(256) void softmax2048_kernel(float* __restrict__ gv) {
    __shared__ float red[4];
    const int tid = threadIdx.x;
    float v[8];
    float m = -INFINITY;
    #pragma unroll
    for (int i = 0; i < 8; ++i) { v[i] = gv[tid + (i << 8)]; m = fmaxf(m, v[i]); }
    #pragma unroll
    for (int o = 1; o < 64; o <<= 1) m = fmaxf(m, __shfl_xor(m, o));
    if ((tid & 63) == 0) red[tid >> 6] = m;
    __syncthreads();
    m = fmaxf(fmaxf(red[0], red[1]), fmaxf(red[2], red[3]));
    __syncthreads();
    float s = 0.f;
    #pragma unroll
    for (int i = 0; i < 8; ++i) { v[i] = __expf(v[i] - m); s += v[i]; }
    #pragma unroll
    for (int o = 1; o < 64; o <<= 1) s += __shfl_xor(s, o);
    if ((tid & 63) == 0) red[tid >> 6] = s;
    __syncthreads();
    s = red[0] + red[1] + red[2] + red[3];
    const float inv = 1.f / s;
    #pragma unroll
    for (int i = 0; i < 8; ++i) gv[tid + (i << 8)] = v[i] * inv;
}

__global__ __launch_bounds__(256) void wsum_part_kernel(
    const float* __restrict__ a, const float* __restrict__ t,
    float* __restrict__ partial)
{
    const int b = blockIdx.x, col = threadIdx.x;
    const int base = b * 16;
    float s = 0.f;
    #pragma unroll
    for (int i = 0; i < 16; ++i)
        s += a[base + i] * t[(long)(base + i) * 256 + col];
    partial[b * 256 + col] = s;
}

__global__ __launch_bounds__(256) void head2_kernel(
    const float* __restrict__ partial, const float* __restrict__ hw,
    const float* __restrict__ hb, float* __restrict__ out)
{
    __shared__ float red0[4], red1[4];
    const int tid = threadIdx.x;
    float p = 0.f;
    #pragma unroll 8
    for (int b = 0; b < 128; ++b) p += partial[b * 256 + tid];
    float s0 = p * hw[tid * 2 + 0];
    float s1 = p * hw[tid * 2 + 1];
    #pragma unroll
    for (int o = 1; o < 64; o <<= 1) { s0 += __shfl_xor(s0, o); s1 += __shfl_xor(s1, o); }
    if ((tid & 63) == 0) { red0[tid >> 6] = s0; red1[tid >> 6] = s1; }
    __syncthreads();
    if (tid == 0) {
        out[0] = red0[0] + red0[1] + red0[2] + red0[3] + hb[0];
        out[1] = red1[0] + red1[1] + red1[2] + red1[3] + hb[1];
    }
}

// ---------------------------------------------------------------------------
extern "C" void kernel_launch(void* const* d_in, const int* in_sizes, int n_in,
                              void* d_out, int out_size, void* d_ws, size_t ws_size,
                              hipStream_t stream)
{
    (void)in_sizes; (void)n_in; (void)out_size; (void)ws_size;
    const float* gene_emb = (const float*)d_in[0];
    const float* pre_w1   = (const float*)d_in[3];
    const float* pre_b1   = (const float*)d_in[4];
    const float* pre_w2   = (const float*)d_in[5];
    const float* pre_b2   = (const float*)d_in[6];
    const float* pre_ln_g = (const float*)d_in[7];
    const float* pre_ln_b = (const float*)d_in[8];
    const float* wm       = (const float*)d_in[9];   // [4,4,256,256]
    const float* wsw      = (const float*)d_in[10];  // [3,4,256,256]
    const float* ln_g     = (const float*)d_in[11];  // row 0 (genes)
    const float* ln_b     = (const float*)d_in[12];
    const float* gate_w1  = (const float*)d_in[13];
    const float* gate_b1  = (const float*)d_in[14];
    const float* gate_w2  = (const float*)d_in[15];
    const float* gate_b2  = (const float*)d_in[16];
    const float* tr_w     = (const float*)d_in[17];
    const float* tr_b     = (const float*)d_in[18];
    const float* head_w   = (const float*)d_in[19];
    const float* head_b   = (const float*)d_in[20];
    const u8* adj_pp      = (const u8*)d_in[21];
    const u8* adj_rr      = (const u8*)d_in[22];
    // d_in[1],[2],[23],[24] dead (reaction/metab branches never reach output)

    const long NHf = (long)Gn * Hd; // 524288
    float* tmp0    = (float*)d_ws;                     // [2048][256]
    float* xg      = tmp0 + NHf;                       // [2048][256]
    float* xg1     = xg + NHf;                         // [2048][256]
    float* ctx2    = xg1 + NHf;                        // [2048][512]
    float* g1      = ctx2 + 2 * NHf;                   // [2048][128]
    float* gatev   = g1 + (long)Gn * 128;              // [2048]
    float* partial = gatev + Gn;                       // [128][256]
    int* cnt       = (int*)(partial + 128 * 256);
    u32* bits_pp   = (u32*)(cnt + 64);                 // [2048][64]
    u32* bits_rr   = bits_pp + (long)Gn * 64;
    ushort* qkvb   = (ushort*)(bits_rr + (long)Gn * 64); // 2 x 1572864 bf16
    ushort* bt_hi  = qkvb + 2L * 1572864;              // 16 slots x 65536
    ushort* bt_lo  = bt_hi + 16L * 65536;

    dim3 B256(256), B64g(2048), T64(64), B128(128);
    dim3 gS(64, 4), gGate(64, 2);

    // mask prep + weight pre-split (one pass)
    hipMemsetAsync((void*)cnt, 0, 2 * sizeof(int), stream);
    detect2_kernel<<<dim3(64), B256, 0, stream>>>(adj_pp, cnt);
    pack_mask_kernel<<<dim3(512), B256, 0, stream>>>(adj_pp, cnt, bits_pp, 64, 2048);
    pack_mask_kernel<<<dim3(512), B256, 0, stream>>>(adj_rr, cnt, bits_rr, 64, 2048);
    preconv_kernel<<<dim3(16, 8), B256, 0, stream>>>(pre_w1, pre_w2, wm, wsw,
                                                     gate_w1, tr_w, bt_hi, bt_lo);

    // preprocessor: xg = relu(LN(relu(LN(gene@w1+b1))@w2+b2)); xg1 = xg
    gemm_mfma_kernel<0, 0, 0, 0, 256><<<gS, B128, 0, stream>>>(gene_emb, 256, bt_hi, bt_lo, 0, 0, pre_b1, tmp0, 256);
    ln_kernel<1, 0><<<B64g, T64, 0, stream>>>(tmp0, pre_ln_g, pre_ln_b, xg, nullptr);
    gemm_mfma_kernel<0, 0, 0, 0, 256><<<gS, B128, 0, stream>>>(xg, 256, bt_hi, bt_lo, 1, 0, pre_b2, tmp0, 256);
    ln_kernel<1, 1><<<B64g, T64, 0, stream>>>(tmp0, pre_ln_g, pre_ln_b, xg, xg1);

    // M block: both edge types batched (QKV z=6; attn z=2; Wo fused K=512)
    gemm_mfma_kernel<0, 0, 1, 1, 256><<<dim3(64, 4, 6), B128, 0, stream>>>(xg, 256, bt_hi, bt_lo, 2, 0, nullptr, (float*)qkvb, 256);
    attn_mfma_kernel<<<dim3(8, 128, 2), B128, 0, stream>>>(qkvb, bits_pp, bits_rr, ctx2);
    gemm_mfma_kernel<1, 0, 0, 0, 512><<<gS, B128, 0, stream>>>(ctx2, 512, bt_hi, bt_lo, 5, 9, nullptr, xg1, 256);

    // S block (full self-attn on xg1)
    gemm_mfma_kernel<0, 0, 1, 2, 256><<<dim3(64, 4, 3), B128, 0, stream>>>(xg1, 256, bt_hi, bt_lo, 10, 0, nullptr, (float*)qkvb, 256);
    attn_mfma_kernel<<<dim3(8, 128, 1), B128, 0, stream>>>(qkvb, nullptr, nullptr, ctx2);
    gemm_mfma_kernel<1, 0, 0, 0, 256><<<gS, B128, 0, stream>>>(ctx2, 512, bt_hi, bt_lo, 13, 0, nullptr, xg1, 256);

    // final LN (gene branch)
    ln_kernel<0, 0><<<B64g, T64, 0, stream>>>(xg1, ln_g, ln_b, xg, nullptr);

    // aggregation
    gemm_mfma_kernel<0, 1, 0, 0, 256><<<gGate, B128, 0, stream>>>(xg, 256, bt_hi, bt_lo, 14, 0, gate_b1, g1, 128);
    gate2_kernel<<<dim3(8), B256, 0, stream>>>(g1, gate_w2, gate_b2, gatev);
    softmax2048_kernel<<<dim3(1), B256, 0, stream>>>(gatev);
    gemm_mfma_kernel<0, 1, 0, 0, 256><<<gS, B128, 0, stream>>>(xg, 256, bt_hi, bt_lo, 15, 0, tr_b, tmp0, 256);
    wsum_part_kernel<<<dim3(128), B256, 0, stream>>>(gatev, tmp0, partial);
    head2_kernel<<<dim3(1), B256, 0, stream>>>(partial, head_w, head_b, (float*)d_out);
}

// Round 5
// 254.335 us; speedup vs baseline: 3.7671x; 1.0018x over previous
//
#include <hip/hip_runtime.h>
#include <hip/hip_bf16.h>
#include <cmath>
#include <cstdint>

typedef unsigned int u32;
typedef unsigned char u8;
typedef unsigned short ushort;
typedef __attribute__((ext_vector_type(8))) short short8;
typedef __attribute__((ext_vector_type(4))) float f32x4;
typedef __attribute__((ext_vector_type(4))) unsigned short us4;

#define Gn 2048
#define Hd 256

static __device__ __forceinline__ ushort f2bf(float x) {
    __hip_bfloat16 b = __float2bfloat16(x);
    return *reinterpret_cast<ushort*>(&b);
}

// ---------------------------------------------------------------------------
// Parallel mask dtype detection (64 blocks x 256 thr x 16B = 256KB scan).
// cnt[0]: nonzero bytes at offset%4==0; cnt[1]: elsewhere.
// int32 -> c0>0,c1==0 ; int8 -> both>0 ; f32 -> c0==0
// ---------------------------------------------------------------------------
__global__ __launch_bounds__(256) void detect2_kernel(const u8* __restrict__ src,
                                                      int* __restrict__ cnt) {
    const int idx = blockIdx.x * 256 + threadIdx.x;
    const uint4 w = ((const uint4*)src)[idx];
    int c0 = ((w.x & 0xffu) ? 1 : 0) + ((w.y & 0xffu) ? 1 : 0) +
             ((w.z & 0xffu) ? 1 : 0) + ((w.w & 0xffu) ? 1 : 0);
    int c1 = ((w.x & 0xffffff00u) ? 1 : 0) + ((w.y & 0xffffff00u) ? 1 : 0) +
             ((w.z & 0xffffff00u) ? 1 : 0) + ((w.w & 0xffffff00u) ? 1 : 0);
    #pragma unroll
    for (int o = 1; o < 64; o <<= 1) { c0 += __shfl_xor(c0, o); c1 += __shfl_xor(c1, o); }
    if ((threadIdx.x & 63) == 0) {
        if (c0) atomicAdd(&cnt[0], c0);
        if (c1) atomicAdd(&cnt[1], c1);
    }
}

// pack mask[rows][cols] (True=attend) into bitmask words [rows][cols/32]
__global__ __launch_bounds__(256) void pack_mask_kernel(
    const u8* __restrict__ src, const int* __restrict__ cnt,
    u32* __restrict__ bits, int nwords_per_row, int ncols)
{
    const int idx = blockIdx.x * 256 + threadIdx.x;
    const int row = idx / nwords_per_row;
    const int w = idx - row * nwords_per_row;
    const int f = (cnt[0] > 0) ? ((cnt[1] > 0) ? 1 : 0) : 2;
    u32 v = 0;
    if (f == 1) {
        const uint4* p = (const uint4*)(src + (long)row * ncols + w * 32);
        const uint4 q0 = p[0], q1 = p[1];
        const u32 ws8[8] = {q0.x, q0.y, q0.z, q0.w, q1.x, q1.y, q1.z, q1.w};
        #pragma unroll
        for (int j = 0; j < 8; ++j) {
            const u32 x = ws8[j];
            const u32 m = (((x & 0x7f7f7f7fu) + 0x7f7f7f7fu) | x) & 0x80808080u;
            const u32 b4 = ((m >> 7) & 1u) | ((m >> 14) & 2u) |
                           ((m >> 21) & 4u) | ((m >> 28) & 8u);
            v |= b4 << (j * 4);
        }
    } else if (f == 0) {
        const uint4* p = (const uint4*)((const int*)src + (long)row * ncols + w * 32);
        #pragma unroll
        for (int j = 0; j < 8; ++j) {
            const uint4 q = p[j];
            v |= (q.x ? 1u : 0u) << (j * 4 + 0);
            v |= (q.y ? 1u : 0u) << (j * 4 + 1);
            v |= (q.z ? 1u : 0u) << (j * 4 + 2);
            v |= (q.w ? 1u : 0u) << (j * 4 + 3);
        }
    } else {
        const uint4* p = (const uint4*)((const float*)src + (long)row * ncols + w * 32);
        #pragma unroll
        for (int j = 0; j < 8; ++j) {
            const uint4 q = p[j];
            v |= ((q.x & 0x7fffffffu) ? 1u : 0u) << (j * 4 + 0);
            v |= ((q.y & 0x7fffffffu) ? 1u : 0u) << (j * 4 + 1);
            v |= ((q.z & 0x7fffffffu) ? 1u : 0u) << (j * 4 + 2);
            v |= ((q.w & 0x7fffffffu) ? 1u : 0u) << (j * 4 + 3);
        }
    }
    bits[idx] = v;
}

// ---------------------------------------------------------------------------
// Weight pre-pass: transposed bf16 split arenas Bt_hi[n][k], Bt_lo[n][k].
// slots: 0 pre_w1, 1 pre_w2, 2-5 wm0 QKVO, 6-9 wm1 QKVO, 10-13 ws0 QKVO,
//        14 gate_w1 (ncols=128), 15 tr_w. Grid (16 slots, 8 k-slabs).
// ---------------------------------------------------------------------------
__global__ __launch_bounds__(256) void preconv_kernel(
    const float* __restrict__ pre_w1, const float* __restrict__ pre_w2,
    const float* __restrict__ wm, const float* __restrict__ wsw,
    const float* __restrict__ gate_w1, const float* __restrict__ tr_w,
    ushort* __restrict__ bt_hi, ushort* __restrict__ bt_lo)
{
    const int slot = blockIdx.x;
    const int k0 = blockIdx.y * 32;
    const float* src; int ncols = 256;
    if (slot == 0) src = pre_w1;
    else if (slot == 1) src = pre_w2;
    else if (slot < 6) src = wm + (long)(slot - 2) * 65536;
    else if (slot < 10) src = wm + (long)(4 + slot - 6) * 65536;
    else if (slot < 14) src = wsw + (long)(slot - 10) * 65536;
    else if (slot == 14) { src = gate_w1; ncols = 128; }
    else src = tr_w;

    __shared__ float T[32][257];
    const int tid = threadIdx.x;
    const int lsh = (ncols == 256) ? 6 : 5;
    const int tot = 32 << lsh;
    for (int i = tid; i < tot; i += 256) {
        const int kk = i >> lsh, c4 = (i & ((1 << lsh) - 1)) << 2;
        const float4 v = *(const float4*)&src[(long)(k0 + kk) * ncols + c4];
        T[kk][c4 + 0] = v.x; T[kk][c4 + 1] = v.y;
        T[kk][c4 + 2] = v.z; T[kk][c4 + 3] = v.w;
    }
    __syncthreads();
    if (tid < ncols) {
        ushort hb[32], lb[32];
        #pragma unroll
        for (int kk = 0; kk < 32; ++kk) {
            const float x = T[kk][tid];
            const u32 bi = __float_as_uint(x);
            const ushort h = (ushort)(bi >> 16);
            const float fh = __uint_as_float(bi & 0xffff0000u);
            hb[kk] = h; lb[kk] = f2bf(x - fh);
        }
        ushort* oh = bt_hi + (long)slot * 65536 + tid * 256 + k0;
        ushort* ol = bt_lo + (long)slot * 65536 + tid * 256 + k0;
        #pragma unroll
        for (int q = 0; q < 4; ++q) {
            *(uint4*)&oh[q * 8] = *(const uint4*)&hb[q * 8];
            *(uint4*)&ol[q * 8] = *(const uint4*)&lb[q * 8];
        }
    }
}

// ---------------------------------------------------------------------------
// bf16x3 split-precision MFMA GEMM (~fp32 accurate): C[M,N] (+)= A @ W (+bias)
// Tile 32x64, 2 waves, no LDS; fragments direct from global (L2-resident).
// OUTMODE 1 = QKV bf16 epilogue. Q rows are pre-scaled by 1/sqrt(32)*log2(e)
// so attention softmax runs in the exp2 domain with no per-score scale mul.
// ---------------------------------------------------------------------------
template <int BETA, int RELU, int OUTMODE, int QKVMODE, int KT>
__global__ __launch_bounds__(128) void gemm_mfma_kernel(
    const float* __restrict__ A, int lda,
    const ushort* __restrict__ bt_hi, const ushort* __restrict__ bt_lo,
    int slot0, int slot2, const float* __restrict__ bias,
    float* __restrict__ C, int N)
{
    const int tid = threadIdx.x;
    const int wv = tid >> 6, l = tid & 63;
    const int lr = l & 15, lg = l >> 4;
    const int row = blockIdx.x * 32 + wv * 16 + lr;
    const int col0 = blockIdx.y * 64;
    int slot = slot0, zq = 0, buf = 0;
    if (QKVMODE == 1) {
        const int z = blockIdx.z;
        slot = slot0 + z + z / 3; zq = z % 3; buf = z / 3;
    } else if (QKVMODE == 2) {
        const int z = blockIdx.z;
        slot = slot0 + z; zq = z;
    }
    const ushort* bhb = bt_hi + (long)slot * 65536;
    const ushort* blb = bt_lo + (long)slot * 65536;
    const float* arow = A + (long)row * lda;

    const f32x4 z4 = {0.f, 0.f, 0.f, 0.f};
    f32x4 acc[4] = {z4, z4, z4, z4};

    #pragma unroll
    for (int ks = 0; ks < KT / 32; ++ks) {
        const int k0 = ks * 32;
        const ushort* bh; const ushort* bl;
        if (KT == 512 && k0 >= 256) {
            bh = bt_hi + (long)slot2 * 65536 + (k0 - 256);
            bl = bt_lo + (long)slot2 * 65536 + (k0 - 256);
        } else { bh = bhb + k0; bl = blb + k0; }
        float av[8];
        *(float4*)&av[0] = *(const float4*)&arow[k0 + lg * 8];
        *(float4*)&av[4] = *(const float4*)&arow[k0 + lg * 8 + 4];
        short8 ahi, alo;
        #pragma unroll
        for (int j = 0; j < 8; ++j) {
            const u32 bi = __float_as_uint(av[j]);
            ahi[j] = (short)(bi >> 16);
            const float fh = __uint_as_float(bi & 0xffff0000u);
            alo[j] = (short)f2bf(av[j] - fh);
        }
        #pragma unroll
        for (int f = 0; f < 4; ++f) {
            const long bo = (long)(col0 + f * 16 + lr) * 256 + lg * 8;
            const short8 bhi = *(const short8*)&bh[bo];
            const short8 blo = *(const short8*)&bl[bo];
            acc[f] = __builtin_amdgcn_mfma_f32_16x16x32_bf16(ahi, bhi, acc[f], 0, 0, 0);
            acc[f] = __builtin_amdgcn_mfma_f32_16x16x32_bf16(alo, bhi, acc[f], 0, 0, 0);
            acc[f] = __builtin_amdgcn_mfma_f32_16x16x32_bf16(ahi, blo, acc[f], 0, 0, 0);
        }
    }

    // Q pre-scale: 1/sqrt(32) * log2(e) (exp2-domain softmax)
    const float QS = 0.17677669529663687f * 1.4426950408889634f;

    #pragma unroll
    for (int f = 0; f < 4; ++f) {
        const int col = col0 + f * 16 + lr;
        const float bv = bias ? bias[col] : 0.f;
        #pragma unroll
        for (int r = 0; r < 4; ++r) {
            const int rr = blockIdx.x * 32 + wv * 16 + lg * 4 + r;
            float v = acc[f][r] + bv;
            if (OUTMODE == 1) {
                if (zq == 0) v *= QS;
                ushort* ob = (ushort*)C + (long)buf * 1572864;
                const int h = col >> 5, d = col & 31;
                if (zq < 2) ob[zq * 524288 + ((h * 2048 + rr) << 5) + d] = f2bf(v);
                else        ob[1048576 + ((h * 32 + d) << 11) + rr] = f2bf(v);
            } else {
                if (BETA) v += C[(long)rr * N + col];
                if (RELU) v = fmaxf(v, 0.f);
                C[(long)rr * N + col] = v;
            }
        }
    }
}

// ---------------------------------------------------------------------------
// LayerNorm over rows of 256 (+optional relu) (+optional duplicate store).
// ---------------------------------------------------------------------------
template <int RELU, int DUP>
__global__ __launch_bounds__(64) void ln_kernel(
    const float* __restrict__ X, const float* __restrict__ gw,
    const float* __restrict__ bw, float* __restrict__ Y, float* __restrict__ Y2)
{
    const int row = blockIdx.x, tid = threadIdx.x;
    const float4 x = *(const float4*)&X[(long)row * 256 + (tid << 2)];
    float s = x.x + x.y + x.z + x.w;
    float s2 = x.x * x.x + x.y * x.y + x.z * x.z + x.w * x.w;
    #pragma unroll
    for (int o = 1; o < 64; o <<= 1) { s += __shfl_xor(s, o); s2 += __shfl_xor(s2, o); }
    const float mean = s * (1.f / 256.f);
    const float var = s2 * (1.f / 256.f) - mean * mean;
    const float rs = rsqrtf(var + 1e-5f);
    const float4 g4 = *(const float4*)&gw[tid << 2];
    const float4 b4 = *(const float4*)&bw[tid << 2];
    float4 y;
    y.x = (x.x - mean) * rs * g4.x + b4.x;
    y.y = (x.y - mean) * rs * g4.y + b4.y;
    y.z = (x.z - mean) * rs * g4.z + b4.z;
    y.w = (x.w - mean) * rs * g4.w + b4.w;
    if (RELU) {
        y.x = fmaxf(y.x, 0.f); y.y = fmaxf(y.y, 0.f);
        y.z = fmaxf(y.z, 0.f); y.w = fmaxf(y.w, 0.f);
    }
    *(float4*)&Y[(long)row * 256 + (tid << 2)] = y;
    if (DUP) *(float4*)&Y2[(long)row * 256 + (tid << 2)] = y;
}

// ---------------------------------------------------------------------------
// MFMA flash attention, exp2-domain (Q pre-scaled by 1/sqrt(32)*log2e).
// Swapped operands: lane q = l&15, softmax state lane-local. KVBLK=128,
// k-split x4 (256 threads), LDS merge. P via cvt_pk_bf16 + XOR-swizzled
// 8B-slot LDS. Exact defer-rescale via __ballot. where(mask,s,-1e9) exact
// (fully-masked rows -> uniform).
// ---------------------------------------------------------------------------
template <int MASKED>
__global__ __launch_bounds__(256) void attn_mfma_kernel(
    const ushort* __restrict__ qkvb, const u32* __restrict__ mb0,
    const u32* __restrict__ mb1, float* __restrict__ ctx)
{
    const int zb = blockIdx.z;
    const ushort* qb = qkvb + (long)zb * 1572864;
    const ushort* kb = qb + 524288;
    const ushort* vt = qb + 1048576;
    const u32* maskbits = MASKED ? ((zb == 0) ? mb0 : mb1) : nullptr;
    const int h = blockIdx.x, qt = blockIdx.y;
    const int wv = threadIdx.x >> 6;   // 0..3 (k-split)
    const int l = threadIdx.x & 63;
    const int lq = l & 15, lg = l >> 4;
    const int qglob = qt * 16 + lq;

    __shared__ __align__(16) ushort Pl[4][2048];
    __shared__ float Mm[3][16], Ml[3][16], Macc[3][64][8];

    const short8 qf = *(const short8*)&qb[((h * 2048 + qglob) << 5) + lg * 8];

    float m = -INFINITY, lsum = 0.f;
    f32x4 acc0 = {0.f, 0.f, 0.f, 0.f};
    f32x4 acc1 = {0.f, 0.f, 0.f, 0.f};
    const f32x4 zz = {0.f, 0.f, 0.f, 0.f};
    const int swz = (lq & 7) << 1;

    #pragma unroll 1
    for (int it = 0; it < 4; ++it) {
        const int kbase = wv * 512 + it * 128;
        float sc[32];
        uint4 mwv;
        if (MASKED) mwv = *(const uint4*)&maskbits[qglob * 64 + (kbase >> 5)];
        // ---- QK^T: 8 x (16 keys x 16 q), K-dim 32 = one MFMA each
        #pragma unroll
        for (int s4 = 0; s4 < 8; ++s4) {
            const short8 kf = *(const short8*)
                &kb[((h * 2048 + kbase + s4 * 16 + lq) << 5) + lg * 8];
            const f32x4 sa = __builtin_amdgcn_mfma_f32_16x16x32_bf16(kf, qf, zz, 0, 0, 0);
            if (MASKED) {
                const u32 w = ((const u32*)&mwv)[s4 >> 1];
                const u32 bits = w >> (((s4 & 1) << 4) + (lg << 2));
                #pragma unroll
                for (int r = 0; r < 4; ++r)
                    sc[s4 * 4 + r] = ((bits >> r) & 1u) ? sa[r] : -1e9f;
            } else {
                #pragma unroll
                for (int r = 0; r < 4; ++r) sc[s4 * 4 + r] = sa[r];
            }
        }
        // ---- tile max (tree) + lane-group reduce
        float t[16];
        #pragma unroll
        for (int i = 0; i < 16; ++i) t[i] = fmaxf(sc[i], sc[i + 16]);
        #pragma unroll
        for (int i = 0; i < 8; ++i) t[i] = fmaxf(t[i], t[i + 8]);
        #pragma unroll
        for (int i = 0; i < 4; ++i) t[i] = fmaxf(t[i], t[i + 4]);
        float mt = fmaxf(fmaxf(t[0], t[1]), fmaxf(t[2], t[3]));
        mt = fmaxf(mt, __shfl_xor(mt, 16));
        mt = fmaxf(mt, __shfl_xor(mt, 32));
        const float mn = fmaxf(m, mt);
        // ---- exact defer-rescale: only if some lane's max grew
        if (__ballot(mn != m)) {
            const float fac = __builtin_amdgcn_exp2f(m - mn); // -inf -> 0
            lsum *= fac;
            #pragma unroll
            for (int j = 0; j < 4; ++j) { acc0[j] *= fac; acc1[j] *= fac; }
            m = mn;
        }
        // ---- p = exp2(sc - m), tree-sum
        #pragma unroll
        for (int i = 0; i < 32; ++i) sc[i] = __builtin_amdgcn_exp2f(sc[i] - m);
        #pragma unroll
        for (int i = 0; i < 16; ++i) t[i] = sc[i] + sc[i + 16];
        #pragma unroll
        for (int i = 0; i < 8; ++i) t[i] = t[i] + t[i + 8];
        #pragma unroll
        for (int i = 0; i < 4; ++i) t[i] = t[i] + t[i + 4];
        float ps = (t[0] + t[1]) + (t[2] + t[3]);
        ps += __shfl_xor(ps, 16);
        ps += __shfl_xor(ps, 32);
        lsum += ps;
        // ---- P -> LDS (cvt_pk bf16, XOR-swizzled 8B slots)
        #pragma unroll
        for (int s4 = 0; s4 < 8; ++s4) {
            u32 a, b;
            asm("v_cvt_pk_bf16_f32 %0, %1, %2" : "=v"(a) : "v"(sc[s4*4+0]), "v"(sc[s4*4+1]));
            asm("v_cvt_pk_bf16_f32 %0, %1, %2" : "=v"(b) : "v"(sc[s4*4+2]), "v"(sc[s4*4+3]));
            const int slot = (s4 * 4 + lg) ^ swz;
            uint2 uv; uv.x = a; uv.y = b;
            *(uint2*)&Pl[wv][lq * 128 + slot * 4] = uv;
        }
        // ---- PV: 4 key-chunks x 2 d-halves
        #pragma unroll
        for (int c = 0; c < 4; ++c) {
            const int x = (c * 8 + lg * 2) ^ swz;
            const short8 pf = *(const short8*)&Pl[wv][lq * 128 + x * 4];
            const short8 vf0 = *(const short8*)
                &vt[((h * 32 + lq) << 11) + kbase + c * 32 + lg * 8];
            acc0 = __builtin_amdgcn_mfma_f32_16x16x32_bf16(vf0, pf, acc0, 0, 0, 0);
            const short8 vf1 = *(const short8*)
                &vt[((h * 32 + 16 + lq) << 11) + kbase + c * 32 + lg * 8];
            acc1 = __builtin_amdgcn_mfma_f32_16x16x32_bf16(vf1, pf, acc1, 0, 0, 0);
        }
    }

    // ---- 4-way k-split merge
    if (wv) {
        if (l < 16) { Mm[wv - 1][l] = m; Ml[wv - 1][l] = lsum; }
        #pragma unroll
        for (int j = 0; j < 4; ++j) { Macc[wv - 1][l][j] = acc0[j]; Macc[wv - 1][l][4 + j] = acc1[j]; }
    }
    __syncthreads();
    if (wv == 0) {
        float M = m;
        #pragma unroll
        for (int w = 0; w < 3; ++w) M = fmaxf(M, Mm[w][lq]);
        const float f0 = __builtin_amdgcn_exp2f(m - M);
        float den = lsum * f0;
        float o0[4], o1[4];
        #pragma unroll
        for (int j = 0; j < 4; ++j) { o0[j] = acc0[j] * f0; o1[j] = acc1[j] * f0; }
        #pragma unroll
        for (int w = 0; w < 3; ++w) {
            const float fw = __builtin_amdgcn_exp2f(Mm[w][lq] - M);
            den += Ml[w][lq] * fw;
            #pragma unroll
            for (int j = 0; j < 4; ++j) {
                o0[j] += Macc[w][l][j] * fw;
                o1[j] += Macc[w][l][4 + j] * fw;
            }
        }
        const float inv = 1.f / den;
        float* orow = &ctx[(long)qglob * 512 + zb * 256 + h * 32];
        #pragma unroll
        for (int r = 0; r < 4; ++r) {
            orow[lg * 4 + r] = o0[r] * inv;
            orow[16 + lg * 4 + r] = o1[r] * inv;
        }
    }
}

// ---------------------------------------------------------------------------
// Aggregation tail
// ---------------------------------------------------------------------------
__global__ __launch_bounds__(256) void gate2_kernel(
    const float* __restrict__ g1, const float* __restrict__ w2,
    const float* __restrict__ b2, float* __restrict__ gv)
{
    int g = blockIdx.x * 256 + threadIdx.x;
    float s = 0.f;
    #pragma unroll
    for (int k = 0; k < 128; k += 4) {
        float4 x = *(const float4*)&g1[(long)g * 128 + k];
        float4 w = *(const float4*)&w2[k];
        s += x.x * w.x + x.y * w.y + x.z * w.z + x.w * w.w;
    }
    gv[g] = s + b2[0];
}

__global__ __launch_bounds__(256) void softmax2048_kernel(float* __restrict__ gv) {
    __shared__ float red[4];
    const int tid = threadIdx.x;
    float v[8];
    float m = -INFINITY;
    #pragma unroll
    for (int i = 0; i < 8; ++i) { v[i] = gv[tid + (i << 8)]; m = fmaxf(m, v[i]); }
    #pragma unroll
    for (int o = 1; o < 64; o <<= 1) m = fmaxf(m, __shfl_xor(m, o));
    if ((tid & 63) == 0) red[tid >> 6] = m;
    __syncthreads();
    m = fmaxf(fmaxf(red[0], red[1]), fmaxf(red[2], red[3]));
    __syncthreads();
    float s = 0.f;
    #pragma unroll
    for (int i = 0; i < 8; ++i) { v[i] = __expf(v[i] - m); s += v[i]; }
    #pragma unroll
    for (int o = 1; o < 64; o <<= 1) s += __shfl_xor(s, o);
    if ((tid & 63) == 0) red[tid >> 6] = s;
    __syncthreads();
    s = red[0] + red[1] + red[2] + red[3];
    const float inv = 1.f / s;
    #pragma unroll
    for (int i = 0; i < 8; ++i) gv[tid + (i << 8)] = v[i] * inv;
}

__global__ __launch_bounds__(256) void wsum_part_kernel(
    const float* __restrict__ a, const float* __restrict__ t,
    float* __restrict__ partial)
{
    const int b = blockIdx.x, col = threadIdx.x;
    const int base = b * 16;
    float s = 0.f;
    #pragma unroll
    for (int i = 0; i < 16; ++i)
        s += a[base + i] * t[(long)(base + i) * 256 + col];
    partial[b * 256 + col] = s;
}

__global__ __launch_bounds__(256) void head2_kernel(
    const float* __restrict__ partial, const float* __restrict__ hw,
    const float* __restrict__ hb, float* __restrict__ out)
{
    __shared__ float red0[4], red1[4];
    const int tid = threadIdx.x;
    float p = 0.f;
    #pragma unroll 8
    for (int b = 0; b < 128; ++b) p += partial[b * 256 + tid];
    float s0 = p * hw[tid * 2 + 0];
    float s1 = p * hw[tid * 2 + 1];
    #pragma unroll
    for (int o = 1; o < 64; o <<= 1) { s0 += __shfl_xor(s0, o); s1 += __shfl_xor(s1, o); }
    if ((tid & 63) == 0) { red0[tid >> 6] = s0; red1[tid >> 6] = s1; }
    __syncthreads();
    if (tid == 0) {
        out[0] = red0[0] + red0[1] + red0[2] + red0[3] + hb[0];
        out[1] = red1[0] + red1[1] + red1[2] + red1[3] + hb[1];
    }
}

// ---------------------------------------------------------------------------
extern "C" void kernel_launch(void* const* d_in, const int* in_sizes, int n_in,
                              void* d_out, int out_size, void* d_ws, size_t ws_size,
                              hipStream_t stream)
{
    (void)in_sizes; (void)n_in; (void)out_size; (void)ws_size;
    const float* gene_emb = (const float*)d_in[0];
    const float* pre_w1   = (const float*)d_in[3];
    const float* pre_b1   = (const float*)d_in[4];
    const float* pre_w2   = (const float*)d_in[5];
    const float* pre_b2   = (const float*)d_in[6];
    const float* pre_ln_g = (const float*)d_in[7];
    const float* pre_ln_b = (const float*)d_in[8];
    const float* wm       = (const float*)d_in[9];   // [4,4,256,256]
    const float* wsw      = (const float*)d_in[10];  // [3,4,256,256]
    const float* ln_g     = (const float*)d_in[11];  // row 0 (genes)
    const float* ln_b     = (const float*)d_in[12];
    const float* gate_w1  = (const float*)d_in[13];
    const float* gate_b1  = (const float*)d_in[14];
    const float* gate_w2  = (const float*)d_in[15];
    const float* gate_b2  = (const float*)d_in[16];
    const float* tr_w     = (const float*)d_in[17];
    const float* tr_b     = (const float*)d_in[18];
    const float* head_w   = (const float*)d_in[19];
    const float* head_b   = (const float*)d_in[20];
    const u8* adj_pp      = (const u8*)d_in[21];
    const u8* adj_rr      = (const u8*)d_in[22];
    // d_in[1],[2],[23],[24] dead (reaction/metab branches never reach output)

    const long NHf = (long)Gn * Hd; // 524288
    float* tmp0    = (float*)d_ws;                     // [2048][256]
    float* xg      = tmp0 + NHf;                       // [2048][256]
    float* xg1     = xg + NHf;                         // [2048][256]
    float* ctx2    = xg1 + NHf;                        // [2048][512]
    float* g1      = ctx2 + 2 * NHf;                   // [2048][128]
    float* gatev   = g1 + (long)Gn * 128;              // [2048]
    float* partial = gatev + Gn;                       // [128][256]
    int* cnt       = (int*)(partial + 128 * 256);
    u32* bits_pp   = (u32*)(cnt + 64);                 // [2048][64]
    u32* bits_rr   = bits_pp + (long)Gn * 64;
    ushort* qkvb   = (ushort*)(bits_rr + (long)Gn * 64); // 2 x 1572864 bf16
    ushort* bt_hi  = qkvb + 2L * 1572864;              // 16 slots x 65536
    ushort* bt_lo  = bt_hi + 16L * 65536;

    dim3 B256(256), B64g(2048), T64(64), B128(128);
    dim3 gS(64, 4), gGate(64, 2);

    // mask prep + weight pre-split
    hipMemsetAsync((void*)cnt, 0, 2 * sizeof(int), stream);
    detect2_kernel<<<dim3(64), B256, 0, stream>>>(adj_pp, cnt);
    pack_mask_kernel<<<dim3(512), B256, 0, stream>>>(adj_pp, cnt, bits_pp, 64, 2048);
    pack_mask_kernel<<<dim3(512), B256, 0, stream>>>(adj_rr, cnt, bits_rr, 64, 2048);
    preconv_kernel<<<dim3(16, 8), B256, 0, stream>>>(pre_w1, pre_w2, wm, wsw,
                                                     gate_w1, tr_w, bt_hi, bt_lo);

    // preprocessor: xg = relu(LN(relu(LN(gene@w1+b1))@w2+b2)); xg1 = xg
    gemm_mfma_kernel<0, 0, 0, 0, 256><<<gS, B128, 0, stream>>>(gene_emb, 256, bt_hi, bt_lo, 0, 0, pre_b1, tmp0, 256);
    ln_kernel<1, 0><<<B64g, T64, 0, stream>>>(tmp0, pre_ln_g, pre_ln_b, xg, nullptr);
    gemm_mfma_kernel<0, 0, 0, 0, 256><<<gS, B128, 0, stream>>>(xg, 256, bt_hi, bt_lo, 1, 0, pre_b2, tmp0, 256);
    ln_kernel<1, 1><<<B64g, T64, 0, stream>>>(tmp0, pre_ln_g, pre_ln_b, xg, xg1);

    // M block: both edge types batched (QKV z=6; attn z=2; Wo fused K=512)
    gemm_mfma_kernel<0, 0, 1, 1, 256><<<dim3(64, 4, 6), B128, 0, stream>>>(xg, 256, bt_hi, bt_lo, 2, 0, nullptr, (float*)qkvb, 256);
    attn_mfma_kernel<1><<<dim3(8, 128, 2), B256, 0, stream>>>(qkvb, bits_pp, bits_rr, ctx2);
    gemm_mfma_kernel<1, 0, 0, 0, 512><<<gS, B128, 0, stream>>>(ctx2, 512, bt_hi, bt_lo, 5, 9, nullptr, xg1, 256);

    // S block (full self-attn on xg1)
    gemm_mfma_kernel<0, 0, 1, 2, 256><<<dim3(64, 4, 3), B128, 0, stream>>>(xg1, 256, bt_hi, bt_lo, 10, 0, nullptr, (float*)qkvb, 256);
    attn_mfma_kernel<0><<<dim3(8, 128, 1), B256, 0, stream>>>(qkvb, nullptr, nullptr, ctx2);
    gemm_mfma_kernel<1, 0, 0, 0, 256><<<gS, B128, 0, stream>>>(ctx2, 512, bt_hi, bt_lo, 13, 0, nullptr, xg1, 256);

    // final LN (gene branch)
    ln_kernel<0, 0><<<B64g, T64, 0, stream>>>(xg1, ln_g, ln_b, xg, nullptr);

    // aggregation
    gemm_mfma_kernel<0, 1, 0, 0, 256><<<gGate, B128, 0, stream>>>(xg, 256, bt_hi, bt_lo, 14, 0, gate_b1, g1, 128);
    gate2_kernel<<<dim3(8), B256, 0, stream>>>(g1, gate_w2, gate_b2, gatev);
    softmax2048_kernel<<<dim3(1), B256, 0, stream>>>(gatev);
    gemm_mfma_kernel<0, 1, 0, 0, 256><<<gS, B128, 0, stream>>>(xg, 256, bt_hi, bt_lo, 15, 0, tr_b, tmp0, 256);
    wsum_part_kernel<<<dim3(128), B256, 0, stream>>>(gatev, tmp0, partial);
    head2_kernel<<<dim3(1), B256, 0, stream>>>(partial, head_w, head_b, (float*)d_out);
}

// Round 6
// 229.148 us; speedup vs baseline: 4.1811x; 1.1099x over previous
//
#include <hip/hip_runtime.h>
#include <hip/hip_bf16.h>
#include <cmath>
#include <cstdint>

typedef unsigned int u32;
typedef unsigned char u8;
typedef unsigned short ushort;
typedef __attribute__((ext_vector_type(8))) short short8;
typedef __attribute__((ext_vector_type(4))) float f32x4;
typedef __attribute__((ext_vector_type(16))) float f32x16;

#define Gn 2048
#define Hd 256

static __device__ __forceinline__ ushort f2bf(float x) {
    __hip_bfloat16 b = __float2bfloat16(x);
    return *reinterpret_cast<ushort*>(&b);
}

// ---------------------------------------------------------------------------
// Parallel mask dtype detection (64 blocks x 256 thr x 16B = 256KB scan).
// cnt[0]: nonzero bytes at offset%4==0; cnt[1]: elsewhere.
// int32 -> c0>0,c1==0 ; int8 -> both>0 ; f32 -> c0==0
// ---------------------------------------------------------------------------
__global__ __launch_bounds__(256) void detect2_kernel(const u8* __restrict__ src,
                                                      int* __restrict__ cnt) {
    const int idx = blockIdx.x * 256 + threadIdx.x;
    const uint4 w = ((const uint4*)src)[idx];
    int c0 = ((w.x & 0xffu) ? 1 : 0) + ((w.y & 0xffu) ? 1 : 0) +
             ((w.z & 0xffu) ? 1 : 0) + ((w.w & 0xffu) ? 1 : 0);
    int c1 = ((w.x & 0xffffff00u) ? 1 : 0) + ((w.y & 0xffffff00u) ? 1 : 0) +
             ((w.z & 0xffffff00u) ? 1 : 0) + ((w.w & 0xffffff00u) ? 1 : 0);
    #pragma unroll
    for (int o = 1; o < 64; o <<= 1) { c0 += __shfl_xor(c0, o); c1 += __shfl_xor(c1, o); }
    if ((threadIdx.x & 63) == 0) {
        if (c0) atomicAdd(&cnt[0], c0);
        if (c1) atomicAdd(&cnt[1], c1);
    }
}

// pack mask[rows][cols] (True=attend) into bitmask words [rows][cols/32]
__global__ __launch_bounds__(256) void pack_mask_kernel(
    const u8* __restrict__ src, const int* __restrict__ cnt,
    u32* __restrict__ bits, int nwords_per_row, int ncols)
{
    const int idx = blockIdx.x * 256 + threadIdx.x;
    const int row = idx / nwords_per_row;
    const int w = idx - row * nwords_per_row;
    const int f = (cnt[0] > 0) ? ((cnt[1] > 0) ? 1 : 0) : 2;
    u32 v = 0;
    if (f == 1) {
        const uint4* p = (const uint4*)(src + (long)row * ncols + w * 32);
        const uint4 q0 = p[0], q1 = p[1];
        const u32 ws8[8] = {q0.x, q0.y, q0.z, q0.w, q1.x, q1.y, q1.z, q1.w};
        #pragma unroll
        for (int j = 0; j < 8; ++j) {
            const u32 x = ws8[j];
            const u32 m = (((x & 0x7f7f7f7fu) + 0x7f7f7f7fu) | x) & 0x80808080u;
            const u32 b4 = ((m >> 7) & 1u) | ((m >> 14) & 2u) |
                           ((m >> 21) & 4u) | ((m >> 28) & 8u);
            v |= b4 << (j * 4);
        }
    } else if (f == 0) {
        const uint4* p = (const uint4*)((const int*)src + (long)row * ncols + w * 32);
        #pragma unroll
        for (int j = 0; j < 8; ++j) {
            const uint4 q = p[j];
            v |= (q.x ? 1u : 0u) << (j * 4 + 0);
            v |= (q.y ? 1u : 0u) << (j * 4 + 1);
            v |= (q.z ? 1u : 0u) << (j * 4 + 2);
            v |= (q.w ? 1u : 0u) << (j * 4 + 3);
        }
    } else {
        const uint4* p = (const uint4*)((const float*)src + (long)row * ncols + w * 32);
        #pragma unroll
        for (int j = 0; j < 8; ++j) {
            const uint4 q = p[j];
            v |= ((q.x & 0x7fffffffu) ? 1u : 0u) << (j * 4 + 0);
            v |= ((q.y & 0x7fffffffu) ? 1u : 0u) << (j * 4 + 1);
            v |= ((q.z & 0x7fffffffu) ? 1u : 0u) << (j * 4 + 2);
            v |= ((q.w & 0x7fffffffu) ? 1u : 0u) << (j * 4 + 3);
        }
    }
    bits[idx] = v;
}

// ---------------------------------------------------------------------------
// Weight pre-pass: transposed bf16 split arenas Bt_hi[n][k], Bt_lo[n][k].
// slots: 0 pre_w1, 1 pre_w2, 2-5 wm0 QKVO, 6-9 wm1 QKVO, 10-13 ws0 QKVO,
//        14 gate_w1 (ncols=128), 15 tr_w. Grid (16 slots, 8 k-slabs).
// ---------------------------------------------------------------------------
__global__ __launch_bounds__(256) void preconv_kernel(
    const float* __restrict__ pre_w1, const float* __restrict__ pre_w2,
    const float* __restrict__ wm, const float* __restrict__ wsw,
    const float* __restrict__ gate_w1, const float* __restrict__ tr_w,
    ushort* __restrict__ bt_hi, ushort* __restrict__ bt_lo)
{
    const int slot = blockIdx.x;
    const int k0 = blockIdx.y * 32;
    const float* src; int ncols = 256;
    if (slot == 0) src = pre_w1;
    else if (slot == 1) src = pre_w2;
    else if (slot < 6) src = wm + (long)(slot - 2) * 65536;
    else if (slot < 10) src = wm + (long)(4 + slot - 6) * 65536;
    else if (slot < 14) src = wsw + (long)(slot - 10) * 65536;
    else if (slot == 14) { src = gate_w1; ncols = 128; }
    else src = tr_w;

    __shared__ float T[32][257];
    const int tid = threadIdx.x;
    const int lsh = (ncols == 256) ? 6 : 5;
    const int tot = 32 << lsh;
    for (int i = tid; i < tot; i += 256) {
        const int kk = i >> lsh, c4 = (i & ((1 << lsh) - 1)) << 2;
        const float4 v = *(const float4*)&src[(long)(k0 + kk) * ncols + c4];
        T[kk][c4 + 0] = v.x; T[kk][c4 + 1] = v.y;
        T[kk][c4 + 2] = v.z; T[kk][c4 + 3] = v.w;
    }
    __syncthreads();
    if (tid < ncols) {
        ushort hb[32], lb[32];
        #pragma unroll
        for (int kk = 0; kk < 32; ++kk) {
            const float x = T[kk][tid];
            const u32 bi = __float_as_uint(x);
            const ushort h = (ushort)(bi >> 16);
            const float fh = __uint_as_float(bi & 0xffff0000u);
            hb[kk] = h; lb[kk] = f2bf(x - fh);
        }
        ushort* oh = bt_hi + (long)slot * 65536 + tid * 256 + k0;
        ushort* ol = bt_lo + (long)slot * 65536 + tid * 256 + k0;
        #pragma unroll
        for (int q = 0; q < 4; ++q) {
            *(uint4*)&oh[q * 8] = *(const uint4*)&hb[q * 8];
            *(uint4*)&ol[q * 8] = *(const uint4*)&lb[q * 8];
        }
    }
}

// ---------------------------------------------------------------------------
// bf16x3 split-precision MFMA GEMM (~fp32 accurate): C[M,N] (+)= A @ W (+bias)
// Tile 32x64, 2 waves, no LDS; fragments direct from global (L2-resident).
// OUTMODE 1 = QKV bf16 epilogue. Q rows are pre-scaled by 1/sqrt(32)*log2(e)
// so attention softmax runs in the exp2 domain with no per-score scale mul.
// ---------------------------------------------------------------------------
template <int BETA, int RELU, int OUTMODE, int QKVMODE, int KT>
__global__ __launch_bounds__(128) void gemm_mfma_kernel(
    const float* __restrict__ A, int lda,
    const ushort* __restrict__ bt_hi, const ushort* __restrict__ bt_lo,
    int slot0, int slot2, const float* __restrict__ bias,
    float* __restrict__ C, int N)
{
    const int tid = threadIdx.x;
    const int wv = tid >> 6, l = tid & 63;
    const int lr = l & 15, lg = l >> 4;
    const int row = blockIdx.x * 32 + wv * 16 + lr;
    const int col0 = blockIdx.y * 64;
    int slot = slot0, zq = 0, buf = 0;
    if (QKVMODE == 1) {
        const int z = blockIdx.z;
        slot = slot0 + z + z / 3; zq = z % 3; buf = z / 3;
    } else if (QKVMODE == 2) {
        const int z = blockIdx.z;
        slot = slot0 + z; zq = z;
    }
    const ushort* bhb = bt_hi + (long)slot * 65536;
    const ushort* blb = bt_lo + (long)slot * 65536;
    const float* arow = A + (long)row * lda;

    const f32x4 z4 = {0.f, 0.f, 0.f, 0.f};
    f32x4 acc[4] = {z4, z4, z4, z4};

    #pragma unroll
    for (int ks = 0; ks < KT / 32; ++ks) {
        const int k0 = ks * 32;
        const ushort* bh; const ushort* bl;
        if (KT == 512 && k0 >= 256) {
            bh = bt_hi + (long)slot2 * 65536 + (k0 - 256);
            bl = bt_lo + (long)slot2 * 65536 + (k0 - 256);
        } else { bh = bhb + k0; bl = blb + k0; }
        float av[8];
        *(float4*)&av[0] = *(const float4*)&arow[k0 + lg * 8];
        *(float4*)&av[4] = *(const float4*)&arow[k0 + lg * 8 + 4];
        short8 ahi, alo;
        #pragma unroll
        for (int j = 0; j < 8; ++j) {
            const u32 bi = __float_as_uint(av[j]);
            ahi[j] = (short)(bi >> 16);
            const float fh = __uint_as_float(bi & 0xffff0000u);
            alo[j] = (short)f2bf(av[j] - fh);
        }
        #pragma unroll
        for (int f = 0; f < 4; ++f) {
            const long bo = (long)(col0 + f * 16 + lr) * 256 + lg * 8;
            const short8 bhi = *(const short8*)&bh[bo];
            const short8 blo = *(const short8*)&bl[bo];
            acc[f] = __builtin_amdgcn_mfma_f32_16x16x32_bf16(ahi, bhi, acc[f], 0, 0, 0);
            acc[f] = __builtin_amdgcn_mfma_f32_16x16x32_bf16(alo, bhi, acc[f], 0, 0, 0);
            acc[f] = __builtin_amdgcn_mfma_f32_16x16x32_bf16(ahi, blo, acc[f], 0, 0, 0);
        }
    }

    // Q pre-scale: 1/sqrt(32) * log2(e) (exp2-domain softmax)
    const float QS = 0.17677669529663687f * 1.4426950408889634f;

    #pragma unroll
    for (int f = 0; f < 4; ++f) {
        const int col = col0 + f * 16 + lr;
        const float bv = bias ? bias[col] : 0.f;
        #pragma unroll
        for (int r = 0; r < 4; ++r) {
            const int rr = blockIdx.x * 32 + wv * 16 + lg * 4 + r;
            float v = acc[f][r] + bv;
            if (OUTMODE == 1) {
                if (zq == 0) v *= QS;
                ushort* ob = (ushort*)C + (long)buf * 1572864;
                const int h = col >> 5, d = col & 31;
                if (zq < 2) ob[zq * 524288 + ((h * 2048 + rr) << 5) + d] = f2bf(v);
                else        ob[1048576 + ((h * 32 + d) << 11) + rr] = f2bf(v);
            } else {
                if (BETA) v += C[(long)rr * N + col];
                if (RELU) v = fmaxf(v, 0.f);
                C[(long)rr * N + col] = v;
            }
        }
    }
}

// ---------------------------------------------------------------------------
// LayerNorm over rows of 256 (+optional relu) (+optional duplicate store).
// ---------------------------------------------------------------------------
template <int RELU, int DUP>
__global__ __launch_bounds__(64) void ln_kernel(
    const float* __restrict__ X, const float* __restrict__ gw,
    const float* __restrict__ bw, float* __restrict__ Y, float* __restrict__ Y2)
{
    const int row = blockIdx.x, tid = threadIdx.x;
    const float4 x = *(const float4*)&X[(long)row * 256 + (tid << 2)];
    float s = x.x + x.y + x.z + x.w;
    float s2 = x.x * x.x + x.y * x.y + x.z * x.z + x.w * x.w;
    #pragma unroll
    for (int o = 1; o < 64; o <<= 1) { s += __shfl_xor(s, o); s2 += __shfl_xor(s2, o); }
    const float mean = s * (1.f / 256.f);
    const float var = s2 * (1.f / 256.f) - mean * mean;
    const float rs = rsqrtf(var + 1e-5f);
    const float4 g4 = *(const float4*)&gw[tid << 2];
    const float4 b4 = *(const float4*)&bw[tid << 2];
    float4 y;
    y.x = (x.x - mean) * rs * g4.x + b4.x;
    y.y = (x.y - mean) * rs * g4.y + b4.y;
    y.z = (x.z - mean) * rs * g4.z + b4.z;
    y.w = (x.w - mean) * rs * g4.w + b4.w;
    if (RELU) {
        y.x = fmaxf(y.x, 0.f); y.y = fmaxf(y.y, 0.f);
        y.z = fmaxf(y.z, 0.f); y.w = fmaxf(y.w, 0.f);
    }
    *(float4*)&Y[(long)row * 256 + (tid << 2)] = y;
    if (DUP) *(float4*)&Y2[(long)row * 256 + (tid << 2)] = y;
}

// ---------------------------------------------------------------------------
// MFMA flash attention v3: 32x32x16 swapped MFMA, fully in-register P.
//   S^T = mfma(K,Q)x2 -> lane owns q=l&31, 16 scores (keys crow(r,hi)).
//   Softmax: in-lane tree + one shfl_xor(32). P -> bf16 via v_cvt_pk_bf16_f32,
//   redistributed to the PV B-fragment with v_permlane32_swap_b32 (NO LDS).
//   ctx^T = mfma(Vt, P) into one f32x16 acc. k-split x4 (4 waves), LDS merge,
//   coalesced store via padded LDS transpose tile.
// Exact where(mask,s,-1e9) semantics (exp2 domain; fully-masked -> uniform).
// ---------------------------------------------------------------------------
template <int MASKED>
__global__ __launch_bounds__(256) void attn_mfma_kernel(
    const ushort* __restrict__ qkvb, const u32* __restrict__ mb0,
    const u32* __restrict__ mb1, float* __restrict__ ctx)
{
    const int zb = blockIdx.z;
    const ushort* qb = qkvb + (long)zb * 1572864;
    const ushort* kb = qb + 524288;
    const ushort* vt = qb + 1048576;
    const u32* maskbits = MASKED ? ((zb == 0) ? mb0 : mb1) : nullptr;
    const int h = blockIdx.x, qt = blockIdx.y;
    const int wv = threadIdx.x >> 6;   // k-split 0..3
    const int l = threadIdx.x & 63;
    const int lq = l & 31;             // q column
    const int hi = l >> 5;
    const int qglob = qt * 32 + lq;

    __shared__ float Mm[3][32], Ml[3][32];
    __shared__ float Macc[3][64][16];
    __shared__ float ctile[32][33];

    // Q B-frags: B[d=(hi)*8+j][q=l&31]; two frags cover d=0..31
    const int qoff = ((h * 2048 + qglob) << 5) + hi * 8;
    const short8 qf0 = *(const short8*)&qb[qoff];
    const short8 qf1 = *(const short8*)&qb[qoff + 16];

    float m = -INFINITY, lsum = 0.f;
    f32x16 acc, zz16;
    #pragma unroll
    for (int i = 0; i < 16; ++i) { acc[i] = 0.f; zz16[i] = 0.f; }

    const int kt0 = wv * 512;
    #pragma unroll 2
    for (int it = 0; it < 16; ++it) {
        const int kbase = kt0 + it * 32;
        // ---- QK^T: A=K rows (key=kbase+l&31), two K=16 MFMAs over d
        const int koff = ((h * 2048 + kbase + lq) << 5) + hi * 8;
        const short8 kf0 = *(const short8*)&kb[koff];
        const short8 kf1 = *(const short8*)&kb[koff + 16];
        f32x16 s = __builtin_amdgcn_mfma_f32_32x32x16_bf16(kf0, qf0, zz16, 0, 0, 0);
        s = __builtin_amdgcn_mfma_f32_32x32x16_bf16(kf1, qf1, s, 0, 0, 0);
        // ---- mask (exact where-semantics); score r -> key crow(r,hi)
        float sc[16];
        if (MASKED) {
            const u32 mw = maskbits[qglob * 64 + (kbase >> 5)];
            #pragma unroll
            for (int g = 0; g < 4; ++g) {
                const u32 nib = mw >> (8 * g + 4 * hi);
                #pragma unroll
                for (int j = 0; j < 4; ++j)
                    sc[4 * g + j] = ((nib >> j) & 1u) ? s[4 * g + j] : -1e9f;
            }
        } else {
            #pragma unroll
            for (int i = 0; i < 16; ++i) sc[i] = s[i];
        }
        // ---- column max: in-lane tree + cross-half shuffle
        float t[8];
        #pragma unroll
        for (int i = 0; i < 8; ++i) t[i] = fmaxf(sc[i], sc[i + 8]);
        #pragma unroll
        for (int i = 0; i < 4; ++i) t[i] = fmaxf(t[i], t[i + 4]);
        float mt = fmaxf(fmaxf(t[0], t[1]), fmaxf(t[2], t[3]));
        mt = fmaxf(mt, __shfl_xor(mt, 32));
        const float mn = fmaxf(m, mt);
        // ---- exact defer-rescale (wave-uniform branch)
        if (__ballot(mn != m)) {
            const float fac = __builtin_amdgcn_exp2f(m - mn); // -inf -> 0
            lsum *= fac;
            #pragma unroll
            for (int i = 0; i < 16; ++i) acc[i] *= fac;
            m = mn;
        }
        // ---- p = exp2(sc - m); column sum
        #pragma unroll
        for (int i = 0; i < 16; ++i) sc[i] = __builtin_amdgcn_exp2f(sc[i] - m);
        #pragma unroll
        for (int i = 0; i < 8; ++i) t[i] = sc[i] + sc[i + 8];
        #pragma unroll
        for (int i = 0; i < 4; ++i) t[i] = t[i] + t[i + 4];
        float ps = (t[0] + t[1]) + (t[2] + t[3]);
        ps += __shfl_xor(ps, 32);
        lsum += ps;
        // ---- P -> bf16 pairs; permlane32_swap builds PV B-frags in-register
        u32 pk[8];
        #pragma unroll
        for (int g = 0; g < 4; ++g) {
            asm("v_cvt_pk_bf16_f32 %0, %1, %2"
                : "=v"(pk[2 * g]) : "v"(sc[4 * g + 0]), "v"(sc[4 * g + 1]));
            asm("v_cvt_pk_bf16_f32 %0, %1, %2"
                : "=v"(pk[2 * g + 1]) : "v"(sc[4 * g + 2]), "v"(sc[4 * g + 3]));
        }
        // keys {8g+4hi+0..3} per pk pair; swap -> B[k=(hi)*8+j][q]
        asm volatile("v_permlane32_swap_b32 %0, %1" : "+v"(pk[0]), "+v"(pk[2]));
        asm volatile("v_permlane32_swap_b32 %0, %1" : "+v"(pk[1]), "+v"(pk[3]));
        asm volatile("v_permlane32_swap_b32 %0, %1" : "+v"(pk[4]), "+v"(pk[6]));
        asm volatile("v_permlane32_swap_b32 %0, %1" : "+v"(pk[5]), "+v"(pk[7]));
        short8 pB0, pB1;
        ((u32*)&pB0)[0] = pk[0]; ((u32*)&pB0)[1] = pk[1];
        ((u32*)&pB0)[2] = pk[2]; ((u32*)&pB0)[3] = pk[3];
        ((u32*)&pB1)[0] = pk[4]; ((u32*)&pB1)[1] = pk[5];
        ((u32*)&pB1)[2] = pk[6]; ((u32*)&pB1)[3] = pk[7];
        // ---- PV: A=Vt rows (d=l&31), keys kbase+{0..15},{16..31}
        const int voff = ((h * 32 + lq) << 11) + kbase + hi * 8;
        const short8 vf0 = *(const short8*)&vt[voff];
        const short8 vf1 = *(const short8*)&vt[voff + 16];
        acc = __builtin_amdgcn_mfma_f32_32x32x16_bf16(vf0, pB0, acc, 0, 0, 0);
        acc = __builtin_amdgcn_mfma_f32_32x32x16_bf16(vf1, pB1, acc, 0, 0, 0);
    }

    // ---- 4-way k-split merge
    if (wv) {
        if (l < 32) { Mm[wv - 1][l] = m; Ml[wv - 1][l] = lsum; }
        #pragma unroll
        for (int i = 0; i < 16; ++i) Macc[wv - 1][l][i] = acc[i];
    }
    __syncthreads();
    if (wv == 0) {
        float M = m;
        #pragma unroll
        for (int w = 0; w < 3; ++w) M = fmaxf(M, Mm[w][lq]);
        const float f0 = __builtin_amdgcn_exp2f(m - M);
        float den = lsum * f0;
        float o[16];
        #pragma unroll
        for (int i = 0; i < 16; ++i) o[i] = acc[i] * f0;
        #pragma unroll
        for (int w = 0; w < 3; ++w) {
            const float fw = __builtin_amdgcn_exp2f(Mm[w][lq] - M);
            den += Ml[w][lq] * fw;
            #pragma unroll
            for (int i = 0; i < 16; ++i) o[i] += Macc[w][l][i] * fw;
        }
        const float inv = 1.f / den;
        #pragma unroll
        for (int i = 0; i < 16; ++i)
            ctile[(i & 3) + 8 * (i >> 2) + 4 * hi][lq] = o[i] * inv;
    }
    __syncthreads();
    {
        const int t = threadIdx.x;
        const int q = t >> 3, d0 = (t & 7) << 2;
        float4 ov;
        ov.x = ctile[d0 + 0][q]; ov.y = ctile[d0 + 1][q];
        ov.z = ctile[d0 + 2][q]; ov.w = ctile[d0 + 3][q];
        *(float4*)&ctx[(long)(qt * 32 + q) * 512 + zb * 256 + h * 32 + d0] = ov;
    }
}

// ---------------------------------------------------------------------------
// Aggregation tail
// ---------------------------------------------------------------------------
__global__ __launch_bounds__(256) void gate2_kernel(
    const float* __restrict__ g1, const float* __restrict__ w2,
    const float* __restrict__ b2, float* __restrict__ gv)
{
    int g = blockIdx.x * 256 + threadIdx.x;
    float s = 0.f;
    #pragma unroll
    for (int k = 0; k < 128; k += 4) {
        float4 x = *(const float4*)&g1[(long)g * 128 + k];
        float4 w = *(const float4*)&w2[k];
        s += x.x * w.x + x.y * w.y + x.z * w.z + x.w * w.w;
    }
    gv[g] = s + b2[0];
}

__global__ __launch_bounds__(256) void softmax2048_kernel(float* __restrict__ gv) {
    __shared__ float red[4];
    const int tid = threadIdx.x;
    float v[8];
    float m = -INFINITY;
    #pragma unroll
    for (int i = 0; i < 8; ++i) { v[i] = gv[tid + (i << 8)]; m = fmaxf(m, v[i]); }
    #pragma unroll
    for (int o = 1; o < 64; o <<= 1) m = fmaxf(m, __shfl_xor(m, o));
    if ((tid & 63) == 0) red[tid >> 6] = m;
    __syncthreads();
    m = fmaxf(fmaxf(red[0], red[1]), fmaxf(red[2], red[3]));
    __syncthreads();
    float s = 0.f;
    #pragma unroll
    for (int i = 0; i < 8; ++i) { v[i] = __expf(v[i] - m); s += v[i]; }
    #pragma unroll
    for (int o = 1; o < 64; o <<= 1) s += __shfl_xor(s, o);
    if ((tid & 63) == 0) red[tid >> 6] = s;
    __syncthreads();
    s = red[0] + red[1] + red[2] + red[3];
    const float inv = 1.f / s;
    #pragma unroll
    for (int i = 0; i < 8; ++i) gv[tid + (i << 8)] = v[i] * inv;
}

__global__ __launch_bounds__(256) void wsum_part_kernel(
    const float* __restrict__ a, const float* __restrict__ t,
    float* __restrict__ partial)
{
    const int b = blockIdx.x, col = threadIdx.x;
    const int base = b * 16;
    float s = 0.f;
    #pragma unroll
    for (int i = 0; i < 16; ++i)
        s += a[base + i] * t[(long)(base + i) * 256 + col];
    partial[b * 256 + col] = s;
}

__global__ __launch_bounds__(256) void head2_kernel(
    const float* __restrict__ partial, const float* __restrict__ hw,
    const float* __restrict__ hb, float* __restrict__ out)
{
    __shared__ float red0[4], red1[4];
    const int tid = threadIdx.x;
    float p = 0.f;
    #pragma unroll 8
    for (int b = 0; b < 128; ++b) p += partial[b * 256 + tid];
    float s0 = p * hw[tid * 2 + 0];
    float s1 = p * hw[tid * 2 + 1];
    #pragma unroll
    for (int o = 1; o < 64; o <<= 1) { s0 += __shfl_xor(s0, o); s1 += __shfl_xor(s1, o); }
    if ((tid & 63) == 0) { red0[tid >> 6] = s0; red1[tid >> 6] = s1; }
    __syncthreads();
    if (tid == 0) {
        out[0] = red0[0] + red0[1] + red0[2] + red0[3] + hb[0];
        out[1] = red1[0] + red1[1] + red1[2] + red1[3] + hb[1];
    }
}

// ---------------------------------------------------------------------------
extern "C" void kernel_launch(void* const* d_in, const int* in_sizes, int n_in,
                              void* d_out, int out_size, void* d_ws, size_t ws_size,
                              hipStream_t stream)
{
    (void)in_sizes; (void)n_in; (void)out_size; (void)ws_size;
    const float* gene_emb = (const float*)d_in[0];
    const float* pre_w1   = (const float*)d_in[3];
    const float* pre_b1   = (const float*)d_in[4];
    const float* pre_w2   = (const float*)d_in[5];
    const float* pre_b2   = (const float*)d_in[6];
    const float* pre_ln_g = (const float*)d_in[7];
    const float* pre_ln_b = (const float*)d_in[8];
    const float* wm       = (const float*)d_in[9];   // [4,4,256,256]
    const float* wsw      = (const float*)d_in[10];  // [3,4,256,256]
    const float* ln_g     = (const float*)d_in[11];  // row 0 (genes)
    const float* ln_b     = (const float*)d_in[12];
    const float* gate_w1  = (const float*)d_in[13];
    const float* gate_b1  = (const float*)d_in[14];
    const float* gate_w2  = (const float*)d_in[15];
    const float* gate_b2  = (const float*)d_in[16];
    const float* tr_w     = (const float*)d_in[17];
    const float* tr_b     = (const float*)d_in[18];
    const float* head_w   = (const float*)d_in[19];
    const float* head_b   = (const float*)d_in[20];
    const u8* adj_pp      = (const u8*)d_in[21];
    const u8* adj_rr      = (const u8*)d_in[22];
    // d_in[1],[2],[23],[24] dead (reaction/metab branches never reach output)

    const long NHf = (long)Gn * Hd; // 524288
    float* tmp0    = (float*)d_ws;                     // [2048][256]
    float* xg      = tmp0 + NHf;                       // [2048][256]
    float* xg1     = xg + NHf;                         // [2048][256]
    float* ctx2    = xg1 + NHf;                        // [2048][512]
    float* g1      = ctx2 + 2 * NHf;                   // [2048][128]
    float* gatev   = g1 + (long)Gn * 128;              // [2048]
    float* partial = gatev + Gn;                       // [128][256]
    int* cnt       = (int*)(partial + 128 * 256);
    u32* bits_pp   = (u32*)(cnt + 64);                 // [2048][64]
    u32* bits_rr   = bits_pp + (long)Gn * 64;
    ushort* qkvb   = (ushort*)(bits_rr + (long)Gn * 64); // 2 x 1572864 bf16
    ushort* bt_hi  = qkvb + 2L * 1572864;              // 16 slots x 65536
    ushort* bt_lo  = bt_hi + 16L * 65536;

    dim3 B256(256), B64g(2048), T64(64), B128(128);
    dim3 gS(64, 4), gGate(64, 2);

    // mask prep + weight pre-split
    hipMemsetAsync((void*)cnt, 0, 2 * sizeof(int), stream);
    detect2_kernel<<<dim3(64), B256, 0, stream>>>(adj_pp, cnt);
    pack_mask_kernel<<<dim3(512), B256, 0, stream>>>(adj_pp, cnt, bits_pp, 64, 2048);
    pack_mask_kernel<<<dim3(512), B256, 0, stream>>>(adj_rr, cnt, bits_rr, 64, 2048);
    preconv_kernel<<<dim3(16, 8), B256, 0, stream>>>(pre_w1, pre_w2, wm, wsw,
                                                     gate_w1, tr_w, bt_hi, bt_lo);

    // preprocessor: xg = relu(LN(relu(LN(gene@w1+b1))@w2+b2)); xg1 = xg
    gemm_mfma_kernel<0, 0, 0, 0, 256><<<gS, B128, 0, stream>>>(gene_emb, 256, bt_hi, bt_lo, 0, 0, pre_b1, tmp0, 256);
    ln_kernel<1, 0><<<B64g, T64, 0, stream>>>(tmp0, pre_ln_g, pre_ln_b, xg, nullptr);
    gemm_mfma_kernel<0, 0, 0, 0, 256><<<gS, B128, 0, stream>>>(xg, 256, bt_hi, bt_lo, 1, 0, pre_b2, tmp0, 256);
    ln_kernel<1, 1><<<B64g, T64, 0, stream>>>(tmp0, pre_ln_g, pre_ln_b, xg, xg1);

    // M block: both edge types batched (QKV z=6; attn z=2; Wo fused K=512)
    gemm_mfma_kernel<0, 0, 1, 1, 256><<<dim3(64, 4, 6), B128, 0, stream>>>(xg, 256, bt_hi, bt_lo, 2, 0, nullptr, (float*)qkvb, 256);
    attn_mfma_kernel<1><<<dim3(8, 64, 2), B256, 0, stream>>>(qkvb, bits_pp, bits_rr, ctx2);
    gemm_mfma_kernel<1, 0, 0, 0, 512><<<gS, B128, 0, stream>>>(ctx2, 512, bt_hi, bt_lo, 5, 9, nullptr, xg1, 256);

    // S block (full self-attn on xg1)
    gemm_mfma_kernel<0, 0, 1, 2, 256><<<dim3(64, 4, 3), B128, 0, stream>>>(xg1, 256, bt_hi, bt_lo, 10, 0, nullptr, (float*)qkvb, 256);
    attn_mfma_kernel<0><<<dim3(8, 64, 1), B256, 0, stream>>>(qkvb, nullptr, nullptr, ctx2);
    gemm_mfma_kernel<1, 0, 0, 0, 256><<<gS, B128, 0, stream>>>(ctx2, 512, bt_hi, bt_lo, 13, 0, nullptr, xg1, 256);

    // final LN (gene branch)
    ln_kernel<0, 0><<<B64g, T64, 0, stream>>>(xg1, ln_g, ln_b, xg, nullptr);

    // aggregation
    gemm_mfma_kernel<0, 1, 0, 0, 256><<<gGate, B128, 0, stream>>>(xg, 256, bt_hi, bt_lo, 14, 0, gate_b1, g1, 128);
    gate2_kernel<<<dim3(8), B256, 0, stream>>>(g1, gate_w2, gate_b2, gatev);
    softmax2048_kernel<<<dim3(1), B256, 0, stream>>>(gatev);
    gemm_mfma_kernel<0, 1, 0, 0, 256><<<gS, B128, 0, stream>>>(xg, 256, bt_hi, bt_lo, 15, 0, tr_b, tmp0, 256);
    wsum_part_kernel<<<dim3(128), B256, 0, stream>>>(gatev, tmp0, partial);
    head2_kernel<<<dim3(1), B256, 0, stream>>>(partial, head_w, head_b, (float*)d_out);
}